// Round 1
// baseline (185.691 us; speedup 1.0000x reference)
//
#include <hip/hip_runtime.h>
#include <stdint.h>

typedef unsigned short u16;
typedef __attribute__((ext_vector_type(4))) float f32x4;
typedef __attribute__((ext_vector_type(8))) short bf16x8;

#define T_SEQ 2048
#define DM 1024
#define NH 16
#define NG 4
#define DH 64

__device__ __forceinline__ u16 f2bf(float f) {
    union { float f; uint32_t u; } v; v.f = f;
    uint32_t r = (v.u + 0x7FFFu + ((v.u >> 16) & 1u)) >> 16;
    return (u16)r;
}
__device__ __forceinline__ float bf2f(u16 u) {
    union { uint32_t u; float f; } v; v.u = ((uint32_t)u) << 16;
    return v.f;
}

__device__ __forceinline__ void async16(const void* g, void* l) {
    __builtin_amdgcn_global_load_lds(
        (const __attribute__((address_space(1))) void*)g,
        (__attribute__((address_space(3))) void*)l,
        16, 0, 0);
}

// ---------------- cast x (f32 -> bf16), 8 elems/thread ----------------
__global__ __launch_bounds__(256) void k_cast_bf16(
    const float* __restrict__ in, u16* __restrict__ out, int n8) {
    int i = blockIdx.x * 256 + threadIdx.x;
    if (i >= n8) return;
    const float4* p = (const float4*)in + (size_t)i * 2;
    float4 a = p[0], b = p[1];
    bf16x8 v;
    v[0] = (short)f2bf(a.x); v[1] = (short)f2bf(a.y);
    v[2] = (short)f2bf(a.z); v[3] = (short)f2bf(a.w);
    v[4] = (short)f2bf(b.x); v[5] = (short)f2bf(b.y);
    v[6] = (short)f2bf(b.z); v[7] = (short)f2bf(b.w);
    ((bf16x8*)out)[i] = v;
}

// ---------------- transpose + cast: src f32 [K][N] -> dst bf16 [N][K] ----------------
__global__ __launch_bounds__(256) void k_transpose_cast(
    const float* __restrict__ src, u16* __restrict__ dst, int K, int N) {
    __shared__ float tile[32][33];
    int tx = threadIdx.x, ty = threadIdx.y;
    int n0 = blockIdx.x * 32, k0 = blockIdx.y * 32;
#pragma unroll
    for (int q = 0; q < 4; q++)
        tile[ty + q * 8][tx] = src[(size_t)(k0 + ty + q * 8) * N + n0 + tx];
    __syncthreads();
#pragma unroll
    for (int q = 0; q < 4; q++)
        dst[(size_t)(n0 + ty + q * 8) * K + k0 + tx] = f2bf(tile[tx][ty + q * 8]);
}

// ---------------- concat bias [bq|bk|bv] -> f32[1536] ----------------
__global__ void k_concat_bias(const float* __restrict__ bq, const float* __restrict__ bk,
                              const float* __restrict__ bv, float* __restrict__ o) {
    int i = blockIdx.x * 256 + threadIdx.x;
    if (i >= 1536) return;
    float v;
    if (i < 1024) v = bq[i];
    else if (i < 1280) v = bk[i - 1024];
    else v = bv[i - 1280];
    o[i] = v;
}

// ---------------- GEMM: C[M][N](f32) = A[M][K](bf16) @ Bt[N][K](bf16)^T + bias ----------------
// 128x128 tile, BK=64, 4 waves (2x2), 16x16x32 MFMA, global_load_lds w/ XOR-swizzle
__global__ __launch_bounds__(256) void k_gemm_bt(
    const u16* __restrict__ A, const u16* __restrict__ Bt,
    const float* __restrict__ bias, float* __restrict__ C,
    int M, int N, int K) {
    __shared__ __align__(16) u16 As[128 * 64];
    __shared__ __align__(16) u16 Bs[128 * 64];
    int tid = threadIdx.x;
    int lane = tid & 63, wid = tid >> 6;
    int wr = wid >> 1, wc = wid & 1;
    int l15 = lane & 15, lhi = lane >> 4;
    int row0 = blockIdx.y * 128, col0 = blockIdx.x * 128;
    f32x4 acc[4][4] = {};

    for (int k0 = 0; k0 < K; k0 += 64) {
#pragma unroll
        for (int i = 0; i < 4; i++) {
            int c = i * 256 + tid;
            int r = c >> 3, ch = c & 7;
            int sch = ch ^ (r & 7);   // pre-swizzle global source chunk
            async16(A + (size_t)(row0 + r) * K + k0 + sch * 8, &As[c * 8]);
            async16(Bt + (size_t)(col0 + r) * K + k0 + sch * 8, &Bs[c * 8]);
        }
        __syncthreads();
#pragma unroll
        for (int ks = 0; ks < 2; ks++) {
            bf16x8 af[4], bfr[4];
#pragma unroll
            for (int m = 0; m < 4; m++) {
                int r = wr * 64 + m * 16 + l15;
                int kb = (ks * 64 + lhi * 16) ^ ((r & 7) << 4);  // swizzled read
                af[m] = *(const bf16x8*)((const char*)As + r * 128 + kb);
            }
#pragma unroll
            for (int n = 0; n < 4; n++) {
                int r = wc * 64 + n * 16 + l15;
                int kb = (ks * 64 + lhi * 16) ^ ((r & 7) << 4);
                bfr[n] = *(const bf16x8*)((const char*)Bs + r * 128 + kb);
            }
#pragma unroll
            for (int m = 0; m < 4; m++)
#pragma unroll
                for (int n = 0; n < 4; n++)
                    acc[m][n] = __builtin_amdgcn_mfma_f32_16x16x32_bf16(
                        af[m], bfr[n], acc[m][n], 0, 0, 0);
        }
        __syncthreads();
    }
#pragma unroll
    for (int n = 0; n < 4; n++) {
        int col = col0 + wc * 64 + n * 16 + l15;
        float bv = bias[col];
#pragma unroll
        for (int m = 0; m < 4; m++) {
            int row = row0 + wr * 64 + m * 16 + lhi * 4;
#pragma unroll
            for (int i = 0; i < 4; i++)
                C[(size_t)(row + i) * N + col] = acc[m][n][i] + bv;
        }
    }
}

// ---------------- RoPE + scatter ----------------
// qkv f32 [B*T][1536] -> Q bf16 [B][H][T][64] (x0.125), K bf16 [B][G][T][64], Vt bf16 [B][G][64][T]
__global__ __launch_bounds__(256) void k_rope_scatter(
    const float* __restrict__ qkv, u16* __restrict__ Qo,
    u16* __restrict__ Ko, u16* __restrict__ Vto) {
    int bt = blockIdx.x;
    int t = bt & (T_SEQ - 1), b = bt >> 11;
    const float* row = qkv + (size_t)bt * 1536;
    __shared__ float cs[32], sn[32];
    int tid = threadIdx.x;
    if (tid < 32) {
        float freq = expf(-((float)(2 * tid) / 64.0f) * 9.210340371976184f);
        float ang = (float)t * freq;
        cs[tid] = cosf(ang);
        sn[tid] = sinf(ang);
    }
    __syncthreads();
    // Q: 512 pairs
    for (int j = tid; j < 512; j += 256) {
        int hq = j >> 5, i = j & 31;
        float xe = row[2 * j], xo = row[2 * j + 1];
        float c = cs[i], s = sn[i];
        float re = (xe * c - xo * s) * 0.125f;
        float ro = (xe * s + xo * c) * 0.125f;
        size_t base = (((size_t)(b * NH + hq)) * T_SEQ + t) * DH + 2 * i;
        Qo[base] = f2bf(re); Qo[base + 1] = f2bf(ro);
    }
    // K: 128 pairs
    if (tid < 128) {
        int g = tid >> 5, i = tid & 31;
        float xe = row[1024 + 2 * tid], xo = row[1024 + 2 * tid + 1];
        float c = cs[i], s = sn[i];
        float re = xe * c - xo * s;
        float ro = xe * s + xo * c;
        size_t base = (((size_t)(b * NG + g)) * T_SEQ + t) * DH + 2 * i;
        Ko[base] = f2bf(re); Ko[base + 1] = f2bf(ro);
    }
    // V: 256 elems, transposed store
    {
        int g = tid >> 6, d = tid & 63;
        float v = row[1280 + tid];
        Vto[(((size_t)(b * NG + g)) * DH + d) * T_SEQ + t] = f2bf(v);
    }
}

// ---------------- causal GQA flash attention ----------------
// Q [B*H][T][64], K [B*G][T][64], Vt [B*G][64][T], out bf16 [B*T][1024]
__global__ __launch_bounds__(256) void k_attn(
    const u16* __restrict__ Q, const u16* __restrict__ K,
    const u16* __restrict__ Vt, u16* __restrict__ Aout) {
    int qt = blockIdx.x;          // q tile (64 rows)
    int bh = blockIdx.y;          // b*16 + h
    int b = bh >> 4, h = bh & 15, g = h >> 2;
    int tid = threadIdx.x;
    int lane = tid & 63, wid = tid >> 6;
    int l15 = lane & 15, lhi = lane >> 4;

    const u16* Qp = Q + ((size_t)bh * T_SEQ + qt * 64) * DH;
    const u16* Kp = K + ((size_t)(b * NG + g)) * T_SEQ * DH;
    const u16* Vp = Vt + ((size_t)(b * NG + g)) * DH * T_SEQ;

    __shared__ __align__(16) u16 Ks[64 * 64];
    __shared__ __align__(16) u16 Vs[64 * 64];
    __shared__ __align__(16) u16 Ps[4][16 * 80];   // stride 80 to dodge bank conflicts

    // Q fragments in registers (wave rows: qt*64 + wid*16 + l15)
    bf16x8 qf[2];
#pragma unroll
    for (int ks = 0; ks < 2; ks++)
        qf[ks] = *(const bf16x8*)(Qp + (size_t)(wid * 16 + l15) * DH + ks * 32 + lhi * 8);

    f32x4 of[4] = {};
    float m_i[4] = {-3.0e38f, -3.0e38f, -3.0e38f, -3.0e38f};
    float l_i[4] = {0.f, 0.f, 0.f, 0.f};

    int nt = qt + 1;
    for (int it = 0; it < nt; it++) {
        int s0 = it * 64;
        // stage K tile [64 s][64 d] and Vt tile [64 d][64 s], swizzled source
#pragma unroll
        for (int i = 0; i < 2; i++) {
            int c = i * 256 + tid;
            int r = c >> 3, ch = c & 7, sch = ch ^ (r & 7);
            async16(Kp + (size_t)(s0 + r) * DH + sch * 8, &Ks[c * 8]);
        }
#pragma unroll
        for (int i = 0; i < 2; i++) {
            int c = i * 256 + tid;
            int r = c >> 3, ch = c & 7, sch = ch ^ (r & 7);
            async16(Vp + (size_t)r * T_SEQ + s0 + sch * 8, &Vs[c * 8]);
        }
        __syncthreads();

        // S = Q K^T  (rows: t local = lhi*4+i, cols: s local = n*16+l15)
        f32x4 sf[4] = {};
#pragma unroll
        for (int ks = 0; ks < 2; ks++) {
#pragma unroll
            for (int n = 0; n < 4; n++) {
                int sr = n * 16 + l15;
                int kb = (ks * 64 + lhi * 16) ^ ((sr & 7) << 4);
                bf16x8 kf = *(const bf16x8*)((const char*)Ks + sr * 128 + kb);
                sf[n] = __builtin_amdgcn_mfma_f32_16x16x32_bf16(qf[ks], kf, sf[n], 0, 0, 0);
            }
        }
        // causal mask on diagonal tile
        if (it == nt - 1) {
#pragma unroll
            for (int n = 0; n < 4; n++) {
                int sl = n * 16 + l15;
#pragma unroll
                for (int i = 0; i < 4; i++) {
                    int ql = wid * 16 + lhi * 4 + i;
                    if (sl > ql) sf[n][i] = -3.0e38f;
                }
            }
        }
        // online softmax (row r lives across the 16-lane group, element i)
        float pm[4];
#pragma unroll
        for (int i = 0; i < 4; i++)
            pm[i] = fmaxf(fmaxf(sf[0][i], sf[1][i]), fmaxf(sf[2][i], sf[3][i]));
#pragma unroll
        for (int off = 1; off <= 8; off <<= 1)
#pragma unroll
            for (int i = 0; i < 4; i++)
                pm[i] = fmaxf(pm[i], __shfl_xor(pm[i], off));
        float sc[4];
#pragma unroll
        for (int i = 0; i < 4; i++) {
            float mn = fmaxf(m_i[i], pm[i]);
            sc[i] = __expf(m_i[i] - mn);
            m_i[i] = mn;
        }
        float rs[4] = {0.f, 0.f, 0.f, 0.f};
#pragma unroll
        for (int n = 0; n < 4; n++)
#pragma unroll
            for (int i = 0; i < 4; i++) {
                float p = __expf(sf[n][i] - m_i[i]);
                sf[n][i] = p;
                rs[i] += p;
            }
#pragma unroll
        for (int off = 1; off <= 8; off <<= 1)
#pragma unroll
            for (int i = 0; i < 4; i++)
                rs[i] += __shfl_xor(rs[i], off);
#pragma unroll
        for (int i = 0; i < 4; i++) {
            l_i[i] = l_i[i] * sc[i] + rs[i];
        }
        // rescale O
#pragma unroll
        for (int n = 0; n < 4; n++)
#pragma unroll
            for (int i = 0; i < 4; i++)
                of[n][i] *= sc[i];
        // P -> LDS (bf16), per-wave private buffer, stride 80
        u16* Pw = Ps[wid];
#pragma unroll
        for (int n = 0; n < 4; n++)
#pragma unroll
            for (int i = 0; i < 4; i++)
                Pw[(lhi * 4 + i) * 80 + n * 16 + l15] = f2bf(sf[n][i]);
        // O += P V   (A = P from LDS, B = V from transposed LDS tile)
#pragma unroll
        for (int ks = 0; ks < 2; ks++) {
            bf16x8 pf = *(const bf16x8*)(Pw + l15 * 80 + ks * 32 + lhi * 8);
#pragma unroll
            for (int n = 0; n < 4; n++) {
                int dr = n * 16 + l15;
                int kb = (ks * 64 + lhi * 16) ^ ((dr & 7) << 4);
                bf16x8 vf = *(const bf16x8*)((const char*)Vs + dr * 128 + kb);
                of[n] = __builtin_amdgcn_mfma_f32_16x16x32_bf16(pf, vf, of[n], 0, 0, 0);
            }
        }
        __syncthreads();
    }
    // epilogue: normalize, write [b][t][h*64+d] bf16
#pragma unroll
    for (int n = 0; n < 4; n++)
#pragma unroll
        for (int i = 0; i < 4; i++) {
            int trow = qt * 64 + wid * 16 + lhi * 4 + i;
            float v = of[n][i] / l_i[i];
            Aout[((size_t)(b * T_SEQ + trow)) * DM + h * 64 + n * 16 + l15] = f2bf(v);
        }
}

// ---------------- launch ----------------
extern "C" void kernel_launch(void* const* d_in, const int* in_sizes, int n_in,
                              void* d_out, int out_size, void* d_ws, size_t ws_size,
                              hipStream_t stream) {
    const float* x  = (const float*)d_in[0];
    const float* Wq = (const float*)d_in[1];
    const float* bq = (const float*)d_in[2];
    const float* Wk = (const float*)d_in[3];
    const float* bk = (const float*)d_in[4];
    const float* Wv = (const float*)d_in[5];
    const float* bv = (const float*)d_in[6];
    const float* Wo = (const float*)d_in[7];
    const float* bo = (const float*)d_in[8];
    float* out = (float*)d_out;

    char* ws = (char*)d_ws;
    size_t o = 0;
    u16*   xb    = (u16*)(ws + o);  o += (size_t)4096 * 1024 * 2;   // x bf16
    u16*   wqkvt = (u16*)(ws + o);  o += (size_t)1536 * 1024 * 2;   // [Wq|Wk|Wv]^T bf16
    u16*   wot   = (u16*)(ws + o);  o += (size_t)1024 * 1024 * 2;   // Wo^T bf16
    float* bqkv  = (float*)(ws + o); o += 1536 * 4;
    o = (o + 255) & ~(size_t)255;
    float* qkvt  = (float*)(ws + o); o += (size_t)4096 * 1536 * 4;  // QKV rows f32
    u16*   Qb    = (u16*)(ws + o);  o += (size_t)2 * NH * T_SEQ * DH * 2;
    u16*   Kb    = (u16*)(ws + o);  o += (size_t)2 * NG * T_SEQ * DH * 2;
    u16*   Vtb   = (u16*)(ws + o);  o += (size_t)2 * NG * DH * T_SEQ * 2;
    u16*   attnb = (u16*)(ws + o);  o += (size_t)4096 * 1024 * 2;

    // 1. cast x
    k_cast_bf16<<<2048, 256, 0, stream>>>(x, xb, 4096 * 1024 / 8);
    // 2. weight transposes (bf16)
    k_transpose_cast<<<dim3(32, 32), dim3(32, 8), 0, stream>>>(Wq, wqkvt, 1024, 1024);
    k_transpose_cast<<<dim3(8, 32),  dim3(32, 8), 0, stream>>>(Wk, wqkvt + (size_t)1024 * 1024, 1024, 256);
    k_transpose_cast<<<dim3(8, 32),  dim3(32, 8), 0, stream>>>(Wv, wqkvt + (size_t)1280 * 1024, 1024, 256);
    k_transpose_cast<<<dim3(32, 32), dim3(32, 8), 0, stream>>>(Wo, wot, 1024, 1024);
    // 3. bias concat
    k_concat_bias<<<6, 256, 0, stream>>>(bq, bk, bv, bqkv);
    // 4. QKV projection
    k_gemm_bt<<<dim3(12, 32), 256, 0, stream>>>(xb, wqkvt, bqkv, qkvt, 4096, 1536, 1024);
    // 5. RoPE + scatter (+1/sqrt(64) folded into Q)
    k_rope_scatter<<<4096, 256, 0, stream>>>(qkvt, Qb, Kb, Vtb);
    // 6. attention
    k_attn<<<dim3(32, 32), 256, 0, stream>>>(Qb, Kb, Vtb, attnb);
    // 7. output projection -> d_out
    k_gemm_bt<<<dim3(8, 32), 256, 0, stream>>>(attnb, wot, bo, out, 4096, 1024, 1024);
}

// Round 2
// 137.096 us; speedup vs baseline: 1.3545x; 1.3545x over previous
//
#include <hip/hip_runtime.h>
#include <stdint.h>

typedef unsigned short u16;
typedef __attribute__((ext_vector_type(4))) float f32x4;
typedef __attribute__((ext_vector_type(8))) short bf16x8;

#define T_SEQ 2048
#define DM 1024
#define NH 16
#define NG 4
#define DH 64

__device__ __forceinline__ u16 f2bf(float f) {
    union { float f; uint32_t u; } v; v.f = f;
    uint32_t r = (v.u + 0x7FFFu + ((v.u >> 16) & 1u)) >> 16;
    return (u16)r;
}

__device__ __forceinline__ void async16(const void* g, void* l) {
    __builtin_amdgcn_global_load_lds(
        (const __attribute__((address_space(1))) void*)g,
        (__attribute__((address_space(3))) void*)l,
        16, 0, 0);
}

// ---------------- cast x (f32 -> bf16), 8 elems/thread ----------------
__global__ __launch_bounds__(256) void k_cast_bf16(
    const float* __restrict__ in, u16* __restrict__ out, int n8) {
    int i = blockIdx.x * 256 + threadIdx.x;
    if (i >= n8) return;
    const float4* p = (const float4*)in + (size_t)i * 2;
    float4 a = p[0], b = p[1];
    bf16x8 v;
    v[0] = (short)f2bf(a.x); v[1] = (short)f2bf(a.y);
    v[2] = (short)f2bf(a.z); v[3] = (short)f2bf(a.w);
    v[4] = (short)f2bf(b.x); v[5] = (short)f2bf(b.y);
    v[6] = (short)f2bf(b.z); v[7] = (short)f2bf(b.w);
    ((bf16x8*)out)[i] = v;
}

// ---------------- transpose + cast: src f32 [K][N] -> dst bf16 [N][K] ----------------
__global__ __launch_bounds__(256) void k_transpose_cast(
    const float* __restrict__ src, u16* __restrict__ dst, int K, int N) {
    __shared__ float tile[32][33];
    int tx = threadIdx.x, ty = threadIdx.y;
    int n0 = blockIdx.x * 32, k0 = blockIdx.y * 32;
#pragma unroll
    for (int q = 0; q < 4; q++)
        tile[ty + q * 8][tx] = src[(size_t)(k0 + ty + q * 8) * N + n0 + tx];
    __syncthreads();
#pragma unroll
    for (int q = 0; q < 4; q++)
        dst[(size_t)(n0 + ty + q * 8) * K + k0 + tx] = f2bf(tile[tx][ty + q * 8]);
}

// ---------------- concat bias [bq|bk|bv] -> f32[1536] ----------------
__global__ void k_concat_bias(const float* __restrict__ bq, const float* __restrict__ bk,
                              const float* __restrict__ bv, float* __restrict__ o) {
    int i = blockIdx.x * 256 + threadIdx.x;
    if (i >= 1536) return;
    float v;
    if (i < 1024) v = bq[i];
    else if (i < 1280) v = bk[i - 1024];
    else v = bv[i - 1280];
    o[i] = v;
}

// ---------------- GEMM: C[M][N](f32) = A[M][K](bf16) @ Bt[N][K](bf16)^T + bias ----------------
__global__ __launch_bounds__(256) void k_gemm_bt(
    const u16* __restrict__ A, const u16* __restrict__ Bt,
    const float* __restrict__ bias, float* __restrict__ C,
    int M, int N, int K) {
    __shared__ __align__(16) u16 As[128 * 64];
    __shared__ __align__(16) u16 Bs[128 * 64];
    int tid = threadIdx.x;
    int lane = tid & 63, wid = tid >> 6;
    int wr = wid >> 1, wc = wid & 1;
    int l15 = lane & 15, lhi = lane >> 4;
    int row0 = blockIdx.y * 128, col0 = blockIdx.x * 128;
    f32x4 acc[4][4] = {};

    for (int k0 = 0; k0 < K; k0 += 64) {
#pragma unroll
        for (int i = 0; i < 4; i++) {
            int c = i * 256 + tid;
            int r = c >> 3, ch = c & 7;
            int sch = ch ^ (r & 7);
            async16(A + (size_t)(row0 + r) * K + k0 + sch * 8, &As[c * 8]);
            async16(Bt + (size_t)(col0 + r) * K + k0 + sch * 8, &Bs[c * 8]);
        }
        __syncthreads();
#pragma unroll
        for (int ks = 0; ks < 2; ks++) {
            bf16x8 af[4], bfr[4];
#pragma unroll
            for (int m = 0; m < 4; m++) {
                int r = wr * 64 + m * 16 + l15;
                int kb = (ks * 64 + lhi * 16) ^ ((r & 7) << 4);
                af[m] = *(const bf16x8*)((const char*)As + r * 128 + kb);
            }
#pragma unroll
            for (int n = 0; n < 4; n++) {
                int r = wc * 64 + n * 16 + l15;
                int kb = (ks * 64 + lhi * 16) ^ ((r & 7) << 4);
                bfr[n] = *(const bf16x8*)((const char*)Bs + r * 128 + kb);
            }
#pragma unroll
            for (int m = 0; m < 4; m++)
#pragma unroll
                for (int n = 0; n < 4; n++)
                    acc[m][n] = __builtin_amdgcn_mfma_f32_16x16x32_bf16(
                        af[m], bfr[n], acc[m][n], 0, 0, 0);
        }
        __syncthreads();
    }
#pragma unroll
    for (int n = 0; n < 4; n++) {
        int col = col0 + wc * 64 + n * 16 + l15;
        float bv = bias[col];
#pragma unroll
        for (int m = 0; m < 4; m++) {
            int row = row0 + wr * 64 + m * 16 + lhi * 4;
#pragma unroll
            for (int i = 0; i < 4; i++)
                C[(size_t)(row + i) * N + col] = acc[m][n][i] + bv;
        }
    }
}

// ---------------- RoPE + scatter ----------------
__global__ __launch_bounds__(256) void k_rope_scatter(
    const float* __restrict__ qkv, u16* __restrict__ Qo,
    u16* __restrict__ Ko, u16* __restrict__ Vto) {
    int bt = blockIdx.x;
    int t = bt & (T_SEQ - 1), b = bt >> 11;
    const float* row = qkv + (size_t)bt * 1536;
    __shared__ float cs[32], sn[32];
    int tid = threadIdx.x;
    if (tid < 32) {
        float freq = expf(-((float)(2 * tid) / 64.0f) * 9.210340371976184f);
        float ang = (float)t * freq;
        cs[tid] = cosf(ang);
        sn[tid] = sinf(ang);
    }
    __syncthreads();
    for (int j = tid; j < 512; j += 256) {
        int hq = j >> 5, i = j & 31;
        float xe = row[2 * j], xo = row[2 * j + 1];
        float c = cs[i], s = sn[i];
        float re = (xe * c - xo * s) * 0.125f;
        float ro = (xe * s + xo * c) * 0.125f;
        size_t base = (((size_t)(b * NH + hq)) * T_SEQ + t) * DH + 2 * i;
        Qo[base] = f2bf(re); Qo[base + 1] = f2bf(ro);
    }
    if (tid < 128) {
        int g = tid >> 5, i = tid & 31;
        float xe = row[1024 + 2 * tid], xo = row[1024 + 2 * tid + 1];
        float c = cs[i], s = sn[i];
        float re = xe * c - xo * s;
        float ro = xe * s + xo * c;
        size_t base = (((size_t)(b * NG + g)) * T_SEQ + t) * DH + 2 * i;
        Ko[base] = f2bf(re); Ko[base + 1] = f2bf(ro);
    }
    {
        int g = tid >> 6, d = tid & 63;
        float v = row[1280 + tid];
        Vto[(((size_t)(b * NG + g)) * DH + d) * T_SEQ + t] = f2bf(v);
    }
}

// ---------------- causal GQA flash attention ----------------
// Paired q-tiles (pi, 31-pi): constant 17 KV128-iterations per block.
// KVBLK=128, double-buffered K/V staging (issue-early, drain overlapped).
__global__ __launch_bounds__(256) void k_attn(
    const u16* __restrict__ Q, const u16* __restrict__ K,
    const u16* __restrict__ Vt, u16* __restrict__ Aout) {
    int pi = blockIdx.x;          // 0..15 (tile pair)
    int bh = blockIdx.y;          // b*16 + h
    int b = bh >> 4, h = bh & 15, g = h >> 2;
    int tid = threadIdx.x;
    int lane = tid & 63, wid = tid >> 6;
    int l15 = lane & 15, lhi = lane >> 4;

    const u16* Kp = K + ((size_t)(b * NG + g)) * T_SEQ * DH;
    const u16* Vp = Vt + ((size_t)(b * NG + g)) * DH * T_SEQ;

    __shared__ __align__(16) u16 Ks[2][128 * 64];   // [s][d], 128B rows, swizzled
    __shared__ __align__(16) u16 Vs[2][64 * 128];   // [d][s], 256B rows, swizzled
    __shared__ __align__(16) u16 Ps[4][16 * 72];    // per-wave P half-tile [16 q][64 s]+pad

#pragma unroll 1
    for (int half = 0; half < 2; half++) {
        int qt = half ? (31 - pi) : pi;
        const u16* Qp = Q + ((size_t)bh * T_SEQ + qt * 64) * DH;
        bf16x8 qf[2];
#pragma unroll
        for (int ks = 0; ks < 2; ks++)
            qf[ks] = *(const bf16x8*)(Qp + (size_t)(wid * 16 + l15) * DH + ks * 32 + lhi * 8);

        f32x4 of[4] = {};
        float m_i[4] = {-3.0e38f, -3.0e38f, -3.0e38f, -3.0e38f};
        float l_i[4] = {0.f, 0.f, 0.f, 0.f};

        int nt = (qt + 2) >> 1;   // ceil((qt+1)*64 / 128)

        // prologue: stage tile 0
        {
            int s0 = 0;
#pragma unroll
            for (int i = 0; i < 4; i++) {
                int c = i * 256 + tid;
                int r = c >> 3, ch = c & 7, sch = ch ^ (r & 7);
                async16(Kp + (size_t)(s0 + r) * DH + sch * 8, &Ks[0][c * 8]);
            }
#pragma unroll
            for (int i = 0; i < 4; i++) {
                int c = i * 256 + tid;
                int r = c >> 4, ch = c & 15, sch = ch ^ (r & 7);
                async16(Vp + (size_t)r * T_SEQ + s0 + sch * 8, &Vs[0][c * 8]);
            }
        }
        __syncthreads();

#pragma unroll 1
        for (int it = 0; it < nt; it++) {
            int cur = it & 1;
            // issue next-tile staging FIRST (overlaps with compute below)
            if (it + 1 < nt) {
                int s0 = (it + 1) * 128;
#pragma unroll
                for (int i = 0; i < 4; i++) {
                    int c = i * 256 + tid;
                    int r = c >> 3, ch = c & 7, sch = ch ^ (r & 7);
                    async16(Kp + (size_t)(s0 + r) * DH + sch * 8, &Ks[cur ^ 1][c * 8]);
                }
#pragma unroll
                for (int i = 0; i < 4; i++) {
                    int c = i * 256 + tid;
                    int r = c >> 4, ch = c & 15, sch = ch ^ (r & 7);
                    async16(Vp + (size_t)r * T_SEQ + s0 + sch * 8, &Vs[cur ^ 1][c * 8]);
                }
            }
            const u16* Kc = Ks[cur];
            const u16* Vc = Vs[cur];

            // S = Q K^T : 8 n-frags x 2 ks
            f32x4 sf[8] = {};
            __builtin_amdgcn_s_setprio(1);
#pragma unroll
            for (int ks = 0; ks < 2; ks++)
#pragma unroll
                for (int n = 0; n < 8; n++) {
                    int sr = n * 16 + l15;
                    int kb = (ks * 64 + lhi * 16) ^ ((sr & 7) << 4);
                    bf16x8 kf = *(const bf16x8*)((const char*)Kc + sr * 128 + kb);
                    sf[n] = __builtin_amdgcn_mfma_f32_16x16x32_bf16(qf[ks], kf, sf[n], 0, 0, 0);
                }
            __builtin_amdgcn_s_setprio(0);

            // causal mask (only last iteration can straddle the diagonal)
            if (it == nt - 1) {
                int qrow = qt * 64 + wid * 16 + lhi * 4;
                int sb = it * 128;
#pragma unroll
                for (int n = 0; n < 8; n++) {
                    int sg = sb + n * 16 + l15;
#pragma unroll
                    for (int i = 0; i < 4; i++)
                        if (sg > qrow + i) sf[n][i] = -3.0e38f;
                }
            }

            // online softmax across 128 cols
            float pm[4];
#pragma unroll
            for (int i = 0; i < 4; i++) {
                float a = fmaxf(fmaxf(sf[0][i], sf[1][i]), fmaxf(sf[2][i], sf[3][i]));
                float c = fmaxf(fmaxf(sf[4][i], sf[5][i]), fmaxf(sf[6][i], sf[7][i]));
                pm[i] = fmaxf(a, c);
            }
#pragma unroll
            for (int off = 1; off <= 8; off <<= 1)
#pragma unroll
                for (int i = 0; i < 4; i++)
                    pm[i] = fmaxf(pm[i], __shfl_xor(pm[i], off));
            float sc[4];
#pragma unroll
            for (int i = 0; i < 4; i++) {
                float mn = fmaxf(m_i[i], pm[i]);
                sc[i] = __expf(m_i[i] - mn);
                m_i[i] = mn;
            }
            float rs[4] = {0.f, 0.f, 0.f, 0.f};
#pragma unroll
            for (int n = 0; n < 8; n++)
#pragma unroll
                for (int i = 0; i < 4; i++) {
                    float p = __expf(sf[n][i] - m_i[i]);
                    sf[n][i] = p;
                    rs[i] += p;
                }
#pragma unroll
            for (int off = 1; off <= 8; off <<= 1)
#pragma unroll
                for (int i = 0; i < 4; i++)
                    rs[i] += __shfl_xor(rs[i], off);
#pragma unroll
            for (int i = 0; i < 4; i++)
                l_i[i] = l_i[i] * sc[i] + rs[i];
#pragma unroll
            for (int n = 0; n < 4; n++)
#pragma unroll
                for (int i = 0; i < 4; i++)
                    of[n][i] *= sc[i];

            // PV in two 64-col passes through half-size P buffer
            u16* Pw = Ps[wid];
#pragma unroll
            for (int ph = 0; ph < 2; ph++) {
                // WAR guard: previous pass/iter reads of Pw must retire
                asm volatile("s_waitcnt lgkmcnt(0)" ::: "memory");
                __builtin_amdgcn_sched_barrier(0);
#pragma unroll
                for (int n4 = 0; n4 < 4; n4++)
#pragma unroll
                    for (int i = 0; i < 4; i++)
                        Pw[(lhi * 4 + i) * 72 + n4 * 16 + l15] = f2bf(sf[ph * 4 + n4][i]);
#pragma unroll
                for (int ksh = 0; ksh < 2; ksh++) {
                    bf16x8 pf = *(const bf16x8*)((const char*)Pw + l15 * 144 + ksh * 64 + lhi * 16);
                    int ks = ph * 2 + ksh;
                    __builtin_amdgcn_s_setprio(1);
#pragma unroll
                    for (int n = 0; n < 4; n++) {
                        int dr = n * 16 + l15;
                        int kb = (ks * 64 + lhi * 16) ^ ((dr & 7) << 4);
                        bf16x8 vf = *(const bf16x8*)((const char*)Vc + dr * 256 + kb);
                        of[n] = __builtin_amdgcn_mfma_f32_16x16x32_bf16(pf, vf, of[n], 0, 0, 0);
                    }
                    __builtin_amdgcn_s_setprio(0);
                }
            }
            __syncthreads();
        }

        // epilogue: normalize, write [b][t][h*64+d] bf16
#pragma unroll
        for (int n = 0; n < 4; n++)
#pragma unroll
            for (int i = 0; i < 4; i++) {
                int trow = qt * 64 + wid * 16 + lhi * 4 + i;
                float v = of[n][i] / l_i[i];
                Aout[((size_t)(b * T_SEQ + trow)) * DM + h * 64 + n * 16 + l15] = f2bf(v);
            }
    }
}

// ---------------- launch ----------------
extern "C" void kernel_launch(void* const* d_in, const int* in_sizes, int n_in,
                              void* d_out, int out_size, void* d_ws, size_t ws_size,
                              hipStream_t stream) {
    const float* x  = (const float*)d_in[0];
    const float* Wq = (const float*)d_in[1];
    const float* bq = (const float*)d_in[2];
    const float* Wk = (const float*)d_in[3];
    const float* bk = (const float*)d_in[4];
    const float* Wv = (const float*)d_in[5];
    const float* bv = (const float*)d_in[6];
    const float* Wo = (const float*)d_in[7];
    const float* bo = (const float*)d_in[8];
    float* out = (float*)d_out;

    char* ws = (char*)d_ws;
    size_t o = 0;
    u16*   xb    = (u16*)(ws + o);  o += (size_t)4096 * 1024 * 2;
    u16*   wqkvt = (u16*)(ws + o);  o += (size_t)1536 * 1024 * 2;
    u16*   wot   = (u16*)(ws + o);  o += (size_t)1024 * 1024 * 2;
    float* bqkv  = (float*)(ws + o); o += 1536 * 4;
    o = (o + 255) & ~(size_t)255;
    float* qkvt  = (float*)(ws + o); o += (size_t)4096 * 1536 * 4;
    u16*   Qb    = (u16*)(ws + o);  o += (size_t)2 * NH * T_SEQ * DH * 2;
    u16*   Kb    = (u16*)(ws + o);  o += (size_t)2 * NG * T_SEQ * DH * 2;
    u16*   Vtb   = (u16*)(ws + o);  o += (size_t)2 * NG * DH * T_SEQ * 2;
    u16*   attnb = (u16*)(ws + o);  o += (size_t)4096 * 1024 * 2;

    k_cast_bf16<<<2048, 256, 0, stream>>>(x, xb, 4096 * 1024 / 8);
    k_transpose_cast<<<dim3(32, 32), dim3(32, 8), 0, stream>>>(Wq, wqkvt, 1024, 1024);
    k_transpose_cast<<<dim3(8, 32),  dim3(32, 8), 0, stream>>>(Wk, wqkvt + (size_t)1024 * 1024, 1024, 256);
    k_transpose_cast<<<dim3(8, 32),  dim3(32, 8), 0, stream>>>(Wv, wqkvt + (size_t)1280 * 1024, 1024, 256);
    k_transpose_cast<<<dim3(32, 32), dim3(32, 8), 0, stream>>>(Wo, wot, 1024, 1024);
    k_concat_bias<<<6, 256, 0, stream>>>(bq, bk, bv, bqkv);
    k_gemm_bt<<<dim3(12, 32), 256, 0, stream>>>(xb, wqkvt, bqkv, qkvt, 4096, 1536, 1024);
    k_rope_scatter<<<4096, 256, 0, stream>>>(qkvt, Qb, Kb, Vtb);
    k_attn<<<dim3(16, 32), 256, 0, stream>>>(Qb, Kb, Vtb, attnb);
    k_gemm_bt<<<dim3(8, 32), 256, 0, stream>>>(attnb, wot, bo, out, 4096, 1024, 1024);
}

// Round 3
// 124.255 us; speedup vs baseline: 1.4944x; 1.1033x over previous
//
#include <hip/hip_runtime.h>
#include <stdint.h>

typedef unsigned short u16;
typedef __attribute__((ext_vector_type(4))) float f32x4;
typedef __attribute__((ext_vector_type(8))) short bf16x8;

#define T_SEQ 2048
#define DM 1024
#define NH 16
#define NG 4
#define DH 64
// 0.125 (1/sqrt(64)) * log2(e): softmax computed in exp2 units
#define QSCALE 0.18033688011112042f

__device__ __forceinline__ u16 f2bf(float f) {
    union { float f; uint32_t u; } v; v.f = f;
    uint32_t r = (v.u + 0x7FFFu + ((v.u >> 16) & 1u)) >> 16;
    return (u16)r;
}
__device__ __forceinline__ u16 f2bf_rhu(float f) {   // round-half-up, 2 VALU ops
    union { float f; uint32_t u; } v; v.f = f;
    return (u16)((v.u + 0x8000u) >> 16);
}
__device__ __forceinline__ float bf2f(u16 u) {
    union { uint32_t u; float f; } v; v.u = ((uint32_t)u) << 16;
    return v.f;
}
__device__ __forceinline__ float fexp2(float x) {
#if __has_builtin(__builtin_amdgcn_exp2f)
    return __builtin_amdgcn_exp2f(x);
#else
    return exp2f(x);
#endif
}

__device__ __forceinline__ void async16(const void* g, void* l) {
    __builtin_amdgcn_global_load_lds(
        (const __attribute__((address_space(1))) void*)g,
        (__attribute__((address_space(3))) void*)l,
        16, 0, 0);
}

// ---------------- fused prep: cast x, transpose 4 weights, concat bias ----------------
// grid layout: [0,2048) cast x | [2048,+1024) Wq | +256 Wk | +256 Wv | +1024 Wo | +6 bias
__global__ __launch_bounds__(256) void k_prep(
    const float* __restrict__ x, u16* __restrict__ xb,
    const float* __restrict__ Wq, const float* __restrict__ Wk,
    const float* __restrict__ Wv, const float* __restrict__ Wo,
    u16* __restrict__ wqkvt, u16* __restrict__ wot,
    const float* __restrict__ bq, const float* __restrict__ bk,
    const float* __restrict__ bv, float* __restrict__ bqkv) {
    int blk = blockIdx.x;
    int tid = threadIdx.x;
    if (blk < 2048) {  // cast x -> bf16, 8 elems/thread
        int i = blk * 256 + tid;
        const float4* p = (const float4*)x + (size_t)i * 2;
        float4 a = p[0], b = p[1];
        bf16x8 v;
        v[0] = (short)f2bf(a.x); v[1] = (short)f2bf(a.y);
        v[2] = (short)f2bf(a.z); v[3] = (short)f2bf(a.w);
        v[4] = (short)f2bf(b.x); v[5] = (short)f2bf(b.y);
        v[6] = (short)f2bf(b.z); v[7] = (short)f2bf(b.w);
        ((bf16x8*)xb)[i] = v;
        return;
    }
    int t = blk - 2048;
    if (t >= 2560) {  // bias concat
        int i = (t - 2560) * 256 + tid;
        if (i < 1536) {
            float v;
            if (i < 1024) v = bq[i];
            else if (i < 1280) v = bk[i - 1024];
            else v = bv[i - 1280];
            bqkv[i] = v;
        }
        return;
    }
    const float* src; u16* dst; int N;
    if (t < 1024)      { src = Wq; dst = wqkvt;                      N = 1024; }
    else if (t < 1280) { t -= 1024; src = Wk; dst = wqkvt + (size_t)1024 * 1024; N = 256; }
    else if (t < 1536) { t -= 1280; src = Wv; dst = wqkvt + (size_t)1280 * 1024; N = 256; }
    else               { t -= 1536; src = Wo; dst = wot;             N = 1024; }
    int ntiles = N >> 5;
    int n0 = (t % ntiles) * 32, k0 = (t / ntiles) * 32;
    __shared__ float tile[32][33];
    int tx = tid & 31, ty = tid >> 5;
#pragma unroll
    for (int q = 0; q < 4; q++)
        tile[ty + q * 8][tx] = src[(size_t)(k0 + ty + q * 8) * N + n0 + tx];
    __syncthreads();
#pragma unroll
    for (int q = 0; q < 4; q++)
        dst[(size_t)(n0 + ty + q * 8) * 1024 + k0 + tx] = f2bf(tile[tx][ty + q * 8]);
}

// ---------------- GEMM: C[M][N] = A[M][K](bf16) @ Bt[N][K](bf16)^T + bias ----------------
template <int B16OUT>
__global__ __launch_bounds__(256) void k_gemm_bt(
    const u16* __restrict__ A, const u16* __restrict__ Bt,
    const float* __restrict__ bias, void* __restrict__ Cv,
    int M, int N, int K) {
    __shared__ __align__(16) u16 As[128 * 64];
    __shared__ __align__(16) u16 Bs[128 * 64];
    int tid = threadIdx.x;
    int lane = tid & 63, wid = tid >> 6;
    int wr = wid >> 1, wc = wid & 1;
    int l15 = lane & 15, lhi = lane >> 4;
    int row0 = blockIdx.y * 128, col0 = blockIdx.x * 128;
    f32x4 acc[4][4] = {};

    for (int k0 = 0; k0 < K; k0 += 64) {
#pragma unroll
        for (int i = 0; i < 4; i++) {
            int c = i * 256 + tid;
            int r = c >> 3, ch = c & 7;
            int sch = ch ^ (r & 7);
            async16(A + (size_t)(row0 + r) * K + k0 + sch * 8, &As[c * 8]);
            async16(Bt + (size_t)(col0 + r) * K + k0 + sch * 8, &Bs[c * 8]);
        }
        __syncthreads();
#pragma unroll
        for (int ks = 0; ks < 2; ks++) {
            bf16x8 af[4], bfr[4];
#pragma unroll
            for (int m = 0; m < 4; m++) {
                int r = wr * 64 + m * 16 + l15;
                int kb = (ks * 64 + lhi * 16) ^ ((r & 7) << 4);
                af[m] = *(const bf16x8*)((const char*)As + r * 128 + kb);
            }
#pragma unroll
            for (int n = 0; n < 4; n++) {
                int r = wc * 64 + n * 16 + l15;
                int kb = (ks * 64 + lhi * 16) ^ ((r & 7) << 4);
                bfr[n] = *(const bf16x8*)((const char*)Bs + r * 128 + kb);
            }
#pragma unroll
            for (int m = 0; m < 4; m++)
#pragma unroll
                for (int n = 0; n < 4; n++)
                    acc[m][n] = __builtin_amdgcn_mfma_f32_16x16x32_bf16(
                        af[m], bfr[n], acc[m][n], 0, 0, 0);
        }
        __syncthreads();
    }
#pragma unroll
    for (int n = 0; n < 4; n++) {
        int col = col0 + wc * 64 + n * 16 + l15;
        float bv = bias[col];
#pragma unroll
        for (int m = 0; m < 4; m++) {
            int row = row0 + wr * 64 + m * 16 + lhi * 4;
#pragma unroll
            for (int i = 0; i < 4; i++) {
                float v = acc[m][n][i] + bv;
                if (B16OUT) ((u16*)Cv)[(size_t)(row + i) * N + col] = f2bf(v);
                else        ((float*)Cv)[(size_t)(row + i) * N + col] = v;
            }
        }
    }
}

// ---------------- RoPE + scatter (qkv now bf16) ----------------
// Q gets 0.125*log2e folded in (softmax in exp2 units)
__global__ __launch_bounds__(256) void k_rope_scatter(
    const u16* __restrict__ qkv, u16* __restrict__ Qo,
    u16* __restrict__ Ko, u16* __restrict__ Vto) {
    int bt = blockIdx.x;
    int t = bt & (T_SEQ - 1), b = bt >> 11;
    const u16* row = qkv + (size_t)bt * 1536;
    const uint32_t* row32 = (const uint32_t*)row;
    __shared__ float cs[32], sn[32];
    int tid = threadIdx.x;
    if (tid < 32) {
        float freq = expf(-((float)(2 * tid) / 64.0f) * 9.210340371976184f);
        float ang = (float)t * freq;
        cs[tid] = cosf(ang);
        sn[tid] = sinf(ang);
    }
    __syncthreads();
    for (int j = tid; j < 512; j += 256) {
        int i = j & 31;
        uint32_t w = row32[j];
        float xe = bf2f((u16)w), xo = bf2f((u16)(w >> 16));
        float c = cs[i], s = sn[i];
        float re = (xe * c - xo * s) * QSCALE;
        float ro = (xe * s + xo * c) * QSCALE;
        int hq = j >> 5;
        size_t base = (((size_t)(b * NH + hq)) * T_SEQ + t) * DH + 2 * i;
        Qo[base] = f2bf(re); Qo[base + 1] = f2bf(ro);
    }
    if (tid < 128) {
        int g = tid >> 5, i = tid & 31;
        uint32_t w = row32[512 + tid];
        float xe = bf2f((u16)w), xo = bf2f((u16)(w >> 16));
        float c = cs[i], s = sn[i];
        float re = xe * c - xo * s;
        float ro = xe * s + xo * c;
        size_t base = (((size_t)(b * NG + g)) * T_SEQ + t) * DH + 2 * i;
        Ko[base] = f2bf(re); Ko[base + 1] = f2bf(ro);
    }
    {
        int g = tid >> 6, d = tid & 63;
        Vto[(((size_t)(b * NG + g)) * DH + d) * T_SEQ + t] = row[1280 + tid];
    }
}

// ---------------- causal GQA flash attention ----------------
__global__ __launch_bounds__(256) void k_attn(
    const u16* __restrict__ Q, const u16* __restrict__ K,
    const u16* __restrict__ Vt, u16* __restrict__ Aout) {
    int pi = blockIdx.x;          // 0..15 (tile pair)
    int bh = blockIdx.y;          // b*16 + h
    int b = bh >> 4, h = bh & 15, g = h >> 2;
    int tid = threadIdx.x;
    int lane = tid & 63, wid = tid >> 6;
    int l15 = lane & 15, lhi = lane >> 4;

    const u16* Kp = K + ((size_t)(b * NG + g)) * T_SEQ * DH;
    const u16* Vp = Vt + ((size_t)(b * NG + g)) * DH * T_SEQ;

    __shared__ __align__(16) u16 Ks[2][128 * 64];   // [s][d], swizzled
    __shared__ __align__(16) u16 Vs[2][64 * 128];   // [d][s], swizzled
    __shared__ __align__(16) u16 Ps[4][16 * 72];    // per-wave P half-tile

#pragma unroll 1
    for (int half = 0; half < 2; half++) {
        int qt = half ? (31 - pi) : pi;
        const u16* Qp = Q + ((size_t)bh * T_SEQ + qt * 64) * DH;
        bf16x8 qf[2];
#pragma unroll
        for (int ks = 0; ks < 2; ks++)
            qf[ks] = *(const bf16x8*)(Qp + (size_t)(wid * 16 + l15) * DH + ks * 32 + lhi * 8);

        f32x4 of[4] = {};
        float m_i[4] = {-3.0e38f, -3.0e38f, -3.0e38f, -3.0e38f};
        float l_i[4] = {0.f, 0.f, 0.f, 0.f};

        int nt = (qt + 2) >> 1;

        {   // prologue: stage tile 0
#pragma unroll
            for (int i = 0; i < 4; i++) {
                int c = i * 256 + tid;
                int r = c >> 3, ch = c & 7, sch = ch ^ (r & 7);
                async16(Kp + (size_t)r * DH + sch * 8, &Ks[0][c * 8]);
            }
#pragma unroll
            for (int i = 0; i < 4; i++) {
                int c = i * 256 + tid;
                int r = c >> 4, ch = c & 15, sch = ch ^ (r & 7);
                async16(Vp + (size_t)r * T_SEQ + sch * 8, &Vs[0][c * 8]);
            }
        }
        __syncthreads();

#pragma unroll 1
        for (int it = 0; it < nt; it++) {
            int cur = it & 1;
            if (it + 1 < nt) {
                int s0 = (it + 1) * 128;
#pragma unroll
                for (int i = 0; i < 4; i++) {
                    int c = i * 256 + tid;
                    int r = c >> 3, ch = c & 7, sch = ch ^ (r & 7);
                    async16(Kp + (size_t)(s0 + r) * DH + sch * 8, &Ks[cur ^ 1][c * 8]);
                }
#pragma unroll
                for (int i = 0; i < 4; i++) {
                    int c = i * 256 + tid;
                    int r = c >> 4, ch = c & 15, sch = ch ^ (r & 7);
                    async16(Vp + (size_t)r * T_SEQ + s0 + sch * 8, &Vs[cur ^ 1][c * 8]);
                }
            }
            const u16* Kc = Ks[cur];
            const u16* Vc = Vs[cur];

            // S = Q K^T (exp2 units)
            f32x4 sf[8] = {};
            __builtin_amdgcn_s_setprio(1);
#pragma unroll
            for (int ks = 0; ks < 2; ks++)
#pragma unroll
                for (int n = 0; n < 8; n++) {
                    int sr = n * 16 + l15;
                    int kb = (ks * 64 + lhi * 16) ^ ((sr & 7) << 4);
                    bf16x8 kf = *(const bf16x8*)((const char*)Kc + sr * 128 + kb);
                    sf[n] = __builtin_amdgcn_mfma_f32_16x16x32_bf16(qf[ks], kf, sf[n], 0, 0, 0);
                }
            __builtin_amdgcn_s_setprio(0);

            if (it == nt - 1) {   // causal mask on straddling tile
                int qrow = qt * 64 + wid * 16 + lhi * 4;
                int sb = it * 128;
#pragma unroll
                for (int n = 0; n < 8; n++) {
                    int sg = sb + n * 16 + l15;
#pragma unroll
                    for (int i = 0; i < 4; i++)
                        if (sg > qrow + i) sf[n][i] = -3.0e38f;
                }
            }

            // online softmax, defer-max (T13)
            float pm[4];
#pragma unroll
            for (int i = 0; i < 4; i++) {
                float a = fmaxf(fmaxf(sf[0][i], sf[1][i]), fmaxf(sf[2][i], sf[3][i]));
                float c = fmaxf(fmaxf(sf[4][i], sf[5][i]), fmaxf(sf[6][i], sf[7][i]));
                pm[i] = fmaxf(a, c);
            }
#pragma unroll
            for (int off = 1; off <= 8; off <<= 1)
#pragma unroll
                for (int i = 0; i < 4; i++)
                    pm[i] = fmaxf(pm[i], __shfl_xor(pm[i], off));
            int cond = (pm[0] - m_i[0] <= 8.f) & (pm[1] - m_i[1] <= 8.f) &
                       (pm[2] - m_i[2] <= 8.f) & (pm[3] - m_i[3] <= 8.f);
            if (!__all(cond)) {
                float sc[4];
#pragma unroll
                for (int i = 0; i < 4; i++) {
                    float mn = fmaxf(m_i[i], pm[i]);
                    sc[i] = fexp2(m_i[i] - mn);
                    m_i[i] = mn;
                    l_i[i] *= sc[i];
                }
#pragma unroll
                for (int n = 0; n < 4; n++)
#pragma unroll
                    for (int i = 0; i < 4; i++)
                        of[n][i] *= sc[i];
            }
            float rs[4] = {0.f, 0.f, 0.f, 0.f};
#pragma unroll
            for (int n = 0; n < 8; n++)
#pragma unroll
                for (int i = 0; i < 4; i++) {
                    float p = fexp2(sf[n][i] - m_i[i]);
                    sf[n][i] = p;
                    rs[i] += p;
                }
#pragma unroll
            for (int off = 1; off <= 8; off <<= 1)
#pragma unroll
                for (int i = 0; i < 4; i++)
                    rs[i] += __shfl_xor(rs[i], off);
#pragma unroll
            for (int i = 0; i < 4; i++)
                l_i[i] += rs[i];

            // PV in two 64-col passes through half-size P buffer
            u16* Pw = Ps[wid];
#pragma unroll
            for (int ph = 0; ph < 2; ph++) {
                asm volatile("s_waitcnt lgkmcnt(0)" ::: "memory");
                __builtin_amdgcn_sched_barrier(0);
#pragma unroll
                for (int n4 = 0; n4 < 4; n4++)
#pragma unroll
                    for (int i = 0; i < 4; i++)
                        Pw[(lhi * 4 + i) * 72 + n4 * 16 + l15] = f2bf_rhu(sf[ph * 4 + n4][i]);
#pragma unroll
                for (int ksh = 0; ksh < 2; ksh++) {
                    bf16x8 pf = *(const bf16x8*)((const char*)Pw + l15 * 144 + ksh * 64 + lhi * 16);
                    int ks = ph * 2 + ksh;
                    __builtin_amdgcn_s_setprio(1);
#pragma unroll
                    for (int n = 0; n < 4; n++) {
                        int dr = n * 16 + l15;
                        int kb = (ks * 64 + lhi * 16) ^ ((dr & 7) << 4);
                        bf16x8 vf = *(const bf16x8*)((const char*)Vc + dr * 256 + kb);
                        of[n] = __builtin_amdgcn_mfma_f32_16x16x32_bf16(pf, vf, of[n], 0, 0, 0);
                    }
                    __builtin_amdgcn_s_setprio(0);
                }
            }
            __syncthreads();
        }

#pragma unroll
        for (int n = 0; n < 4; n++)
#pragma unroll
            for (int i = 0; i < 4; i++) {
                int trow = qt * 64 + wid * 16 + lhi * 4 + i;
                float v = of[n][i] / l_i[i];
                Aout[((size_t)(b * T_SEQ + trow)) * DM + h * 64 + n * 16 + l15] = f2bf(v);
            }
    }
}

// ---------------- launch ----------------
extern "C" void kernel_launch(void* const* d_in, const int* in_sizes, int n_in,
                              void* d_out, int out_size, void* d_ws, size_t ws_size,
                              hipStream_t stream) {
    const float* x  = (const float*)d_in[0];
    const float* Wq = (const float*)d_in[1];
    const float* bq = (const float*)d_in[2];
    const float* Wk = (const float*)d_in[3];
    const float* bk = (const float*)d_in[4];
    const float* Wv = (const float*)d_in[5];
    const float* bv = (const float*)d_in[6];
    const float* Wo = (const float*)d_in[7];
    const float* bo = (const float*)d_in[8];

    char* ws = (char*)d_ws;
    size_t o = 0;
    u16*   xb    = (u16*)(ws + o);  o += (size_t)4096 * 1024 * 2;
    u16*   wqkvt = (u16*)(ws + o);  o += (size_t)1536 * 1024 * 2;
    u16*   wot   = (u16*)(ws + o);  o += (size_t)1024 * 1024 * 2;
    float* bqkv  = (float*)(ws + o); o += 1536 * 4;
    o = (o + 255) & ~(size_t)255;
    u16*   qkvt  = (u16*)(ws + o);  o += (size_t)4096 * 1536 * 2;
    u16*   Qb    = (u16*)(ws + o);  o += (size_t)2 * NH * T_SEQ * DH * 2;
    u16*   Kb    = (u16*)(ws + o);  o += (size_t)2 * NG * T_SEQ * DH * 2;
    u16*   Vtb   = (u16*)(ws + o);  o += (size_t)2 * NG * DH * T_SEQ * 2;
    u16*   attnb = (u16*)(ws + o);  o += (size_t)4096 * 1024 * 2;

    k_prep<<<4614, 256, 0, stream>>>(x, xb, Wq, Wk, Wv, Wo, wqkvt, wot, bq, bk, bv, bqkv);
    k_gemm_bt<1><<<dim3(12, 32), 256, 0, stream>>>(xb, wqkvt, bqkv, qkvt, 4096, 1536, 1024);
    k_rope_scatter<<<4096, 256, 0, stream>>>(qkvt, Qb, Kb, Vtb);
    k_attn<<<dim3(16, 32), 256, 0, stream>>>(Qb, Kb, Vtb, attnb);
    k_gemm_bt<0><<<dim3(8, 32), 256, 0, stream>>>(attnb, wot, bo, d_out, 4096, 1024, 1024);
}

// Round 4
// 110.647 us; speedup vs baseline: 1.6782x; 1.1230x over previous
//
#include <hip/hip_runtime.h>
#include <stdint.h>

typedef unsigned short u16;
typedef __attribute__((ext_vector_type(4))) float f32x4;
typedef __attribute__((ext_vector_type(8))) short bf16x8;

#define T_SEQ 2048
#define DM 1024
#define NH 16
#define NG 4
#define DH 64
// 0.125 (1/sqrt(64)) * log2(e): softmax computed in exp2 units
#define QSCALE 0.18033688011112042f

__device__ __forceinline__ u16 f2bf(float f) {
    union { float f; uint32_t u; } v; v.f = f;
    uint32_t r = (v.u + 0x7FFFu + ((v.u >> 16) & 1u)) >> 16;
    return (u16)r;
}
__device__ __forceinline__ u16 f2bf_rhu(float f) {   // round-half-up, 2 VALU ops
    union { float f; uint32_t u; } v; v.f = f;
    return (u16)((v.u + 0x8000u) >> 16);
}
__device__ __forceinline__ float bf2f(u16 u) {
    union { uint32_t u; float f; } v; v.u = ((uint32_t)u) << 16;
    return v.f;
}
__device__ __forceinline__ float fexp2(float x) {
#if __has_builtin(__builtin_amdgcn_exp2f)
    return __builtin_amdgcn_exp2f(x);
#else
    return exp2f(x);
#endif
}

__device__ __forceinline__ void async16(const void* g, void* l) {
    __builtin_amdgcn_global_load_lds(
        (const __attribute__((address_space(1))) void*)g,
        (__attribute__((address_space(3))) void*)l,
        16, 0, 0);
}

// ---------------- fused prep: cast x, transpose 4 weights, bias concat, trig table ----------------
// grid: [0,2048) cast x | [2048,+2560) transposes | +6 bias | +256 trig table
__global__ __launch_bounds__(256) void k_prep(
    const float* __restrict__ x, u16* __restrict__ xb,
    const float* __restrict__ Wq, const float* __restrict__ Wk,
    const float* __restrict__ Wv, const float* __restrict__ Wo,
    u16* __restrict__ wqkvt, u16* __restrict__ wot,
    const float* __restrict__ bq, const float* __restrict__ bk,
    const float* __restrict__ bv, float* __restrict__ bqkv,
    float2* __restrict__ tbl) {
    int blk = blockIdx.x;
    int tid = threadIdx.x;
    if (blk < 2048) {  // cast x -> bf16, 8 elems/thread
        int i = blk * 256 + tid;
        const float4* p = (const float4*)x + (size_t)i * 2;
        float4 a = p[0], b = p[1];
        bf16x8 v;
        v[0] = (short)f2bf(a.x); v[1] = (short)f2bf(a.y);
        v[2] = (short)f2bf(a.z); v[3] = (short)f2bf(a.w);
        v[4] = (short)f2bf(b.x); v[5] = (short)f2bf(b.y);
        v[6] = (short)f2bf(b.z); v[7] = (short)f2bf(b.w);
        ((bf16x8*)xb)[i] = v;
        return;
    }
    int t = blk - 2048;
    if (t >= 2560) {
        int u = t - 2560;
        if (u < 6) {  // bias concat
            int i = u * 256 + tid;
            if (i < 1536) {
                float v;
                if (i < 1024) v = bq[i];
                else if (i < 1280) v = bk[i - 1024];
                else v = bv[i - 1280];
                bqkv[i] = v;
            }
        } else {      // trig table: [2048 t][32 i] -> (cos, sin)
            int idx = (u - 6) * 256 + tid;
            int tt = idx >> 5, i = idx & 31;
            float freq = exp2f(-(float)i * (13.287712379549449f / 32.0f));
            float ang = (float)tt * freq;
            tbl[idx] = make_float2(cosf(ang), sinf(ang));
        }
        return;
    }
    const float* src; u16* dst; int N;
    if (t < 1024)      { src = Wq; dst = wqkvt;                      N = 1024; }
    else if (t < 1280) { t -= 1024; src = Wk; dst = wqkvt + (size_t)1024 * 1024; N = 256; }
    else if (t < 1536) { t -= 1280; src = Wv; dst = wqkvt + (size_t)1280 * 1024; N = 256; }
    else               { t -= 1536; src = Wo; dst = wot;             N = 1024; }
    int ntiles = N >> 5;
    int n0 = (t % ntiles) * 32, k0 = (t / ntiles) * 32;
    __shared__ float tile[32][33];
    int tx = tid & 31, ty = tid >> 5;
#pragma unroll
    for (int q = 0; q < 4; q++)
        tile[ty + q * 8][tx] = src[(size_t)(k0 + ty + q * 8) * N + n0 + tx];
    __syncthreads();
#pragma unroll
    for (int q = 0; q < 4; q++)
        dst[(size_t)(n0 + ty + q * 8) * 1024 + k0 + tx] = f2bf(tile[tx][ty + q * 8]);
}

// ---------------- GEMM 64x128 tile: C[M][N] = A[M][K](bf16) @ Bt[N][K]^T + bias ----------------
// 4 waves as 2(row)x2(col); wave tile 32x64. grid (N/128, M/64).
template <int B16OUT>
__global__ __launch_bounds__(256) void k_gemm_bt(
    const u16* __restrict__ A, const u16* __restrict__ Bt,
    const float* __restrict__ bias, void* __restrict__ Cv,
    int M, int N, int K) {
    __shared__ __align__(16) u16 As[64 * 64];
    __shared__ __align__(16) u16 Bs[128 * 64];
    int tid = threadIdx.x;
    int lane = tid & 63, wid = tid >> 6;
    int wr = wid >> 1, wc = wid & 1;
    int l15 = lane & 15, lhi = lane >> 4;
    int row0 = blockIdx.y * 64, col0 = blockIdx.x * 128;
    f32x4 acc[2][4] = {};

    for (int k0 = 0; k0 < K; k0 += 64) {
#pragma unroll
        for (int i = 0; i < 2; i++) {
            int c = i * 256 + tid;
            int r = c >> 3, ch = c & 7;
            int sch = ch ^ (r & 7);
            async16(A + (size_t)(row0 + r) * K + k0 + sch * 8, &As[c * 8]);
        }
#pragma unroll
        for (int i = 0; i < 4; i++) {
            int c = i * 256 + tid;
            int r = c >> 3, ch = c & 7;
            int sch = ch ^ (r & 7);
            async16(Bt + (size_t)(col0 + r) * K + k0 + sch * 8, &Bs[c * 8]);
        }
        __syncthreads();
#pragma unroll
        for (int ks = 0; ks < 2; ks++) {
            bf16x8 af[2], bfr[4];
#pragma unroll
            for (int m = 0; m < 2; m++) {
                int r = wr * 32 + m * 16 + l15;
                int kb = (ks * 64 + lhi * 16) ^ ((r & 7) << 4);
                af[m] = *(const bf16x8*)((const char*)As + r * 128 + kb);
            }
#pragma unroll
            for (int n = 0; n < 4; n++) {
                int r = wc * 64 + n * 16 + l15;
                int kb = (ks * 64 + lhi * 16) ^ ((r & 7) << 4);
                bfr[n] = *(const bf16x8*)((const char*)Bs + r * 128 + kb);
            }
#pragma unroll
            for (int m = 0; m < 2; m++)
#pragma unroll
                for (int n = 0; n < 4; n++)
                    acc[m][n] = __builtin_amdgcn_mfma_f32_16x16x32_bf16(
                        af[m], bfr[n], acc[m][n], 0, 0, 0);
        }
        __syncthreads();
    }
#pragma unroll
    for (int n = 0; n < 4; n++) {
        int col = col0 + wc * 64 + n * 16 + l15;
        float bv = bias[col];
#pragma unroll
        for (int m = 0; m < 2; m++) {
            int row = row0 + wr * 32 + m * 16 + lhi * 4;
#pragma unroll
            for (int i = 0; i < 4; i++) {
                float v = acc[m][n][i] + bv;
                if (B16OUT) ((u16*)Cv)[(size_t)(row + i) * N + col] = f2bf(v);
                else        ((float*)Cv)[(size_t)(row + i) * N + col] = v;
            }
        }
    }
}

// ---------------- RoPE + scatter (table-driven) ----------------
__global__ __launch_bounds__(256) void k_rope_scatter(
    const u16* __restrict__ qkv, const float2* __restrict__ tbl,
    u16* __restrict__ Qo, u16* __restrict__ Ko, u16* __restrict__ Vto) {
    int bt = blockIdx.x;
    int t = bt & (T_SEQ - 1), b = bt >> 11;
    const u16* row = qkv + (size_t)bt * 1536;
    const uint32_t* row32 = (const uint32_t*)row;
    __shared__ float cs[32], sn[32];
    int tid = threadIdx.x;
    if (tid < 32) {
        float2 p = tbl[t * 32 + tid];
        cs[tid] = p.x; sn[tid] = p.y;
    }
    __syncthreads();
    for (int j = tid; j < 512; j += 256) {
        int i = j & 31;
        uint32_t w = row32[j];
        float xe = bf2f((u16)w), xo = bf2f((u16)(w >> 16));
        float c = cs[i], s = sn[i];
        float re = (xe * c - xo * s) * QSCALE;
        float ro = (xe * s + xo * c) * QSCALE;
        int hq = j >> 5;
        size_t base = (((size_t)(b * NH + hq)) * T_SEQ + t) * DH + 2 * i;
        Qo[base] = f2bf(re); Qo[base + 1] = f2bf(ro);
    }
    if (tid < 128) {
        int g = tid >> 5, i = tid & 31;
        uint32_t w = row32[512 + tid];
        float xe = bf2f((u16)w), xo = bf2f((u16)(w >> 16));
        float c = cs[i], s = sn[i];
        float re = xe * c - xo * s;
        float ro = xe * s + xo * c;
        size_t base = (((size_t)(b * NG + g)) * T_SEQ + t) * DH + 2 * i;
        Ko[base] = f2bf(re); Ko[base + 1] = f2bf(ro);
    }
    {
        int g = tid >> 6, d = tid & 63;
        Vto[(((size_t)(b * NG + g)) * DH + d) * T_SEQ + t] = row[1280 + tid];
    }
}

// ---------------- causal GQA flash attention ----------------
// 1024 blocks (qt descending, backfill balances), single-buffered K/V,
// KVBLK=128, LDS=50176B -> 3 blocks/CU (12 waves/CU).
__global__ __launch_bounds__(256) void k_attn(
    const u16* __restrict__ Q, const u16* __restrict__ K,
    const u16* __restrict__ Vt, u16* __restrict__ Aout) {
    int i0 = blockIdx.x;
    int qt = 31 - (i0 >> 5);      // long blocks dispatch first
    int bh = i0 & 31;
    int b = bh >> 4, h = bh & 15, g = h >> 2;
    int tid = threadIdx.x;
    int lane = tid & 63, wid = tid >> 6;
    int l15 = lane & 15, lhi = lane >> 4;

    const u16* Kp = K + ((size_t)(b * NG + g)) * T_SEQ * DH;
    const u16* Vp = Vt + ((size_t)(b * NG + g)) * DH * T_SEQ;

    __shared__ __align__(16) u16 Ks[128 * 64];     // [s][d], swizzled
    __shared__ __align__(16) u16 Vs[64 * 128];     // [d][s], swizzled
    __shared__ __align__(16) u16 Ps[4][16 * 136];  // per-wave P [16 q][128 s] + pad

    const u16* Qp = Q + ((size_t)bh * T_SEQ + qt * 64) * DH;
    bf16x8 qf[2];
#pragma unroll
    for (int ks = 0; ks < 2; ks++)
        qf[ks] = *(const bf16x8*)(Qp + (size_t)(wid * 16 + l15) * DH + ks * 32 + lhi * 8);

    f32x4 of[4] = {};
    float m_i[4] = {-3.0e38f, -3.0e38f, -3.0e38f, -3.0e38f};
    float l_i[4] = {0.f, 0.f, 0.f, 0.f};

    int nt = (qt + 2) >> 1;
    u16* Pw = Ps[wid];

#pragma unroll 1
    for (int it = 0; it < nt; it++) {
        int s0 = it * 128;
        // stage K [128][64] and V [64][128] (single buffer)
#pragma unroll
        for (int i = 0; i < 4; i++) {
            int c = i * 256 + tid;
            int r = c >> 3, ch = c & 7, sch = ch ^ (r & 7);
            async16(Kp + (size_t)(s0 + r) * DH + sch * 8, &Ks[c * 8]);
        }
#pragma unroll
        for (int i = 0; i < 4; i++) {
            int c = i * 256 + tid;
            int r = c >> 4, ch = c & 15, sch = ch ^ (r & 7);
            async16(Vp + (size_t)r * T_SEQ + s0 + sch * 8, &Vs[c * 8]);
        }
        __syncthreads();

        // S = Q K^T (exp2 units)
        f32x4 sf[8] = {};
        __builtin_amdgcn_s_setprio(1);
#pragma unroll
        for (int ks = 0; ks < 2; ks++)
#pragma unroll
            for (int n = 0; n < 8; n++) {
                int sr = n * 16 + l15;
                int kb = (ks * 64 + lhi * 16) ^ ((sr & 7) << 4);
                bf16x8 kf = *(const bf16x8*)((const char*)Ks + sr * 128 + kb);
                sf[n] = __builtin_amdgcn_mfma_f32_16x16x32_bf16(qf[ks], kf, sf[n], 0, 0, 0);
            }
        __builtin_amdgcn_s_setprio(0);

        if (it == nt - 1) {   // causal mask on straddling tile
            int qrow = qt * 64 + wid * 16 + lhi * 4;
#pragma unroll
            for (int n = 0; n < 8; n++) {
                int sg = s0 + n * 16 + l15;
#pragma unroll
                for (int i = 0; i < 4; i++)
                    if (sg > qrow + i) sf[n][i] = -3.0e38f;
            }
        }

        // online softmax, defer-max (T13)
        float pm[4];
#pragma unroll
        for (int i = 0; i < 4; i++) {
            float a = fmaxf(fmaxf(sf[0][i], sf[1][i]), fmaxf(sf[2][i], sf[3][i]));
            float c = fmaxf(fmaxf(sf[4][i], sf[5][i]), fmaxf(sf[6][i], sf[7][i]));
            pm[i] = fmaxf(a, c);
        }
#pragma unroll
        for (int off = 1; off <= 8; off <<= 1)
#pragma unroll
            for (int i = 0; i < 4; i++)
                pm[i] = fmaxf(pm[i], __shfl_xor(pm[i], off));
        int cond = (pm[0] - m_i[0] <= 8.f) & (pm[1] - m_i[1] <= 8.f) &
                   (pm[2] - m_i[2] <= 8.f) & (pm[3] - m_i[3] <= 8.f);
        if (!__all(cond)) {
            float sc[4];
#pragma unroll
            for (int i = 0; i < 4; i++) {
                float mn = fmaxf(m_i[i], pm[i]);
                sc[i] = fexp2(m_i[i] - mn);
                m_i[i] = mn;
                l_i[i] *= sc[i];
            }
#pragma unroll
            for (int n = 0; n < 4; n++)
#pragma unroll
                for (int i = 0; i < 4; i++)
                    of[n][i] *= sc[i];
        }
        float rs[4] = {0.f, 0.f, 0.f, 0.f};
#pragma unroll
        for (int n = 0; n < 8; n++)
#pragma unroll
            for (int i = 0; i < 4; i++) {
                float p = fexp2(sf[n][i] - m_i[i]);
                sf[n][i] = p;
                rs[i] += p;
            }
#pragma unroll
        for (int off = 1; off <= 8; off <<= 1)
#pragma unroll
            for (int i = 0; i < 4; i++)
                rs[i] += __shfl_xor(rs[i], off);
#pragma unroll
        for (int i = 0; i < 4; i++)
            l_i[i] += rs[i];

        // P -> LDS (per-wave, stride 136 elems, single pass)
#pragma unroll
        for (int n = 0; n < 8; n++)
#pragma unroll
            for (int i = 0; i < 4; i++)
                Pw[(lhi * 4 + i) * 136 + n * 16 + l15] = f2bf_rhu(sf[n][i]);
        asm volatile("" ::: "memory");   // compiler fence; per-wave LDS FIFO orders RAW/WAR

        // O += P V
        __builtin_amdgcn_s_setprio(1);
#pragma unroll
        for (int ks = 0; ks < 4; ks++) {
            bf16x8 pf = *(const bf16x8*)((const char*)Pw + l15 * 272 + ks * 64 + lhi * 16);
#pragma unroll
            for (int n = 0; n < 4; n++) {
                int dr = n * 16 + l15;
                int kb = (ks * 64 + lhi * 16) ^ ((dr & 7) << 4);
                bf16x8 vf = *(const bf16x8*)((const char*)Vs + dr * 256 + kb);
                of[n] = __builtin_amdgcn_mfma_f32_16x16x32_bf16(pf, vf, of[n], 0, 0, 0);
            }
        }
        __builtin_amdgcn_s_setprio(0);
        __syncthreads();   // protect K/V buffers before next stage
    }

#pragma unroll
    for (int n = 0; n < 4; n++)
#pragma unroll
        for (int i = 0; i < 4; i++) {
            int trow = qt * 64 + wid * 16 + lhi * 4 + i;
            float v = of[n][i] / l_i[i];
            Aout[((size_t)(b * T_SEQ + trow)) * DM + h * 64 + n * 16 + l15] = f2bf(v);
        }
}

// ---------------- launch ----------------
extern "C" void kernel_launch(void* const* d_in, const int* in_sizes, int n_in,
                              void* d_out, int out_size, void* d_ws, size_t ws_size,
                              hipStream_t stream) {
    const float* x  = (const float*)d_in[0];
    const float* Wq = (const float*)d_in[1];
    const float* bq = (const float*)d_in[2];
    const float* Wk = (const float*)d_in[3];
    const float* bk = (const float*)d_in[4];
    const float* Wv = (const float*)d_in[5];
    const float* bv = (const float*)d_in[6];
    const float* Wo = (const float*)d_in[7];
    const float* bo = (const float*)d_in[8];

    char* ws = (char*)d_ws;
    size_t o = 0;
    u16*   xb    = (u16*)(ws + o);  o += (size_t)4096 * 1024 * 2;
    u16*   wqkvt = (u16*)(ws + o);  o += (size_t)1536 * 1024 * 2;
    u16*   wot   = (u16*)(ws + o);  o += (size_t)1024 * 1024 * 2;
    float* bqkv  = (float*)(ws + o); o += 1536 * 4;
    o = (o + 255) & ~(size_t)255;
    u16*   qkvt  = (u16*)(ws + o);  o += (size_t)4096 * 1536 * 2;
    u16*   Qb    = (u16*)(ws + o);  o += (size_t)2 * NH * T_SEQ * DH * 2;
    u16*   Kb    = (u16*)(ws + o);  o += (size_t)2 * NG * T_SEQ * DH * 2;
    u16*   Vtb   = (u16*)(ws + o);  o += (size_t)2 * NG * DH * T_SEQ * 2;
    u16*   attnb = (u16*)(ws + o);  o += (size_t)4096 * 1024 * 2;
    float2* tbl  = (float2*)(ws + o); o += (size_t)2048 * 32 * 8;

    k_prep<<<4870, 256, 0, stream>>>(x, xb, Wq, Wk, Wv, Wo, wqkvt, wot, bq, bk, bv, bqkv, tbl);
    k_gemm_bt<1><<<dim3(12, 64), 256, 0, stream>>>(xb, wqkvt, bqkv, qkvt, 4096, 1536, 1024);
    k_rope_scatter<<<4096, 256, 0, stream>>>(qkvt, tbl, Qb, Kb, Vtb);
    k_attn<<<1024, 256, 0, stream>>>(Qb, Kb, Vtb, attnb);
    k_gemm_bt<0><<<dim3(8, 64), 256, 0, stream>>>(attnb, wot, bo, d_out, 4096, 1024, 1024);
}

// Round 5
// 105.455 us; speedup vs baseline: 1.7609x; 1.0492x over previous
//
#include <hip/hip_runtime.h>
#include <stdint.h>

typedef unsigned short u16;
typedef __attribute__((ext_vector_type(4))) float f32x4;
typedef __attribute__((ext_vector_type(8))) short bf16x8;

#define T_SEQ 2048
#define DM 1024
#define NH 16
#define NG 4
#define DH 64
// 0.125 (1/sqrt(64)) * log2(e): softmax computed in exp2 units
#define QSCALE 0.18033688011112042f

__device__ __forceinline__ u16 f2bf(float f) {
    union { float f; uint32_t u; } v; v.f = f;
    uint32_t r = (v.u + 0x7FFFu + ((v.u >> 16) & 1u)) >> 16;
    return (u16)r;
}
__device__ __forceinline__ u16 f2bf_rhu(float f) {   // round-half-up, 2 VALU ops
    union { float f; uint32_t u; } v; v.f = f;
    return (u16)((v.u + 0x8000u) >> 16);
}
__device__ __forceinline__ float bf2f(u16 u) {
    union { uint32_t u; float f; } v; v.u = ((uint32_t)u) << 16;
    return v.f;
}
__device__ __forceinline__ float fexp2(float x) {
#if __has_builtin(__builtin_amdgcn_exp2f)
    return __builtin_amdgcn_exp2f(x);
#else
    return exp2f(x);
#endif
}

__device__ __forceinline__ void async16(const void* g, void* l) {
    __builtin_amdgcn_global_load_lds(
        (const __attribute__((address_space(1))) void*)g,
        (__attribute__((address_space(3))) void*)l,
        16, 0, 0);
}

// ---------------- fused prep: cast x, transpose 4 weights, bias concat, trig table ----------------
__global__ __launch_bounds__(256) void k_prep(
    const float* __restrict__ x, u16* __restrict__ xb,
    const float* __restrict__ Wq, const float* __restrict__ Wk,
    const float* __restrict__ Wv, const float* __restrict__ Wo,
    u16* __restrict__ wqkvt, u16* __restrict__ wot,
    const float* __restrict__ bq, const float* __restrict__ bk,
    const float* __restrict__ bv, float* __restrict__ bqkv,
    float2* __restrict__ tbl) {
    int blk = blockIdx.x;
    int tid = threadIdx.x;
    if (blk < 2048) {  // cast x -> bf16, 8 elems/thread
        int i = blk * 256 + tid;
        const float4* p = (const float4*)x + (size_t)i * 2;
        float4 a = p[0], b = p[1];
        bf16x8 v;
        v[0] = (short)f2bf(a.x); v[1] = (short)f2bf(a.y);
        v[2] = (short)f2bf(a.z); v[3] = (short)f2bf(a.w);
        v[4] = (short)f2bf(b.x); v[5] = (short)f2bf(b.y);
        v[6] = (short)f2bf(b.z); v[7] = (short)f2bf(b.w);
        ((bf16x8*)xb)[i] = v;
        return;
    }
    int t = blk - 2048;
    if (t >= 2560) {
        int u = t - 2560;
        if (u < 6) {  // bias concat
            int i = u * 256 + tid;
            if (i < 1536) {
                float v;
                if (i < 1024) v = bq[i];
                else if (i < 1280) v = bk[i - 1024];
                else v = bv[i - 1280];
                bqkv[i] = v;
            }
        } else {      // trig table: [2048 t][32 i] -> (cos, sin)
            int idx = (u - 6) * 256 + tid;
            int tt = idx >> 5, i = idx & 31;
            float freq = exp2f(-(float)i * (13.287712379549449f / 32.0f));
            float ang = (float)tt * freq;
            tbl[idx] = make_float2(cosf(ang), sinf(ang));
        }
        return;
    }
    const float* src; u16* dst; int N;
    if (t < 1024)      { src = Wq; dst = wqkvt;                      N = 1024; }
    else if (t < 1280) { t -= 1024; src = Wk; dst = wqkvt + (size_t)1024 * 1024; N = 256; }
    else if (t < 1536) { t -= 1280; src = Wv; dst = wqkvt + (size_t)1280 * 1024; N = 256; }
    else               { t -= 1536; src = Wo; dst = wot;             N = 1024; }
    int ntiles = N >> 5;
    int n0 = (t % ntiles) * 32, k0 = (t / ntiles) * 32;
    __shared__ float tile[32][33];
    int tx = tid & 31, ty = tid >> 5;
#pragma unroll
    for (int q = 0; q < 4; q++)
        tile[ty + q * 8][tx] = src[(size_t)(k0 + ty + q * 8) * N + n0 + tx];
    __syncthreads();
#pragma unroll
    for (int q = 0; q < 4; q++)
        dst[(size_t)(n0 + ty + q * 8) * 1024 + k0 + tx] = f2bf(tile[tx][ty + q * 8]);
}

// ---------------- GEMM 64x128 tile: C[M][N] = A[M][K](bf16) @ Bt[N][K]^T + bias ----------------
template <int B16OUT>
__global__ __launch_bounds__(256) void k_gemm_bt(
    const u16* __restrict__ A, const u16* __restrict__ Bt,
    const float* __restrict__ bias, void* __restrict__ Cv,
    int M, int N, int K) {
    __shared__ __align__(16) u16 As[64 * 64];
    __shared__ __align__(16) u16 Bs[128 * 64];
    int tid = threadIdx.x;
    int lane = tid & 63, wid = tid >> 6;
    int wr = wid >> 1, wc = wid & 1;
    int l15 = lane & 15, lhi = lane >> 4;
    int row0 = blockIdx.y * 64, col0 = blockIdx.x * 128;
    f32x4 acc[2][4] = {};

    for (int k0 = 0; k0 < K; k0 += 64) {
#pragma unroll
        for (int i = 0; i < 2; i++) {
            int c = i * 256 + tid;
            int r = c >> 3, ch = c & 7;
            int sch = ch ^ (r & 7);
            async16(A + (size_t)(row0 + r) * K + k0 + sch * 8, &As[c * 8]);
        }
#pragma unroll
        for (int i = 0; i < 4; i++) {
            int c = i * 256 + tid;
            int r = c >> 3, ch = c & 7;
            int sch = ch ^ (r & 7);
            async16(Bt + (size_t)(col0 + r) * K + k0 + sch * 8, &Bs[c * 8]);
        }
        __syncthreads();
#pragma unroll
        for (int ks = 0; ks < 2; ks++) {
            bf16x8 af[2], bfr[4];
#pragma unroll
            for (int m = 0; m < 2; m++) {
                int r = wr * 32 + m * 16 + l15;
                int kb = (ks * 64 + lhi * 16) ^ ((r & 7) << 4);
                af[m] = *(const bf16x8*)((const char*)As + r * 128 + kb);
            }
#pragma unroll
            for (int n = 0; n < 4; n++) {
                int r = wc * 64 + n * 16 + l15;
                int kb = (ks * 64 + lhi * 16) ^ ((r & 7) << 4);
                bfr[n] = *(const bf16x8*)((const char*)Bs + r * 128 + kb);
            }
#pragma unroll
            for (int m = 0; m < 2; m++)
#pragma unroll
                for (int n = 0; n < 4; n++)
                    acc[m][n] = __builtin_amdgcn_mfma_f32_16x16x32_bf16(
                        af[m], bfr[n], acc[m][n], 0, 0, 0);
        }
        __syncthreads();
    }
#pragma unroll
    for (int n = 0; n < 4; n++) {
        int col = col0 + wc * 64 + n * 16 + l15;
        float bv = bias[col];
#pragma unroll
        for (int m = 0; m < 2; m++) {
            int row = row0 + wr * 32 + m * 16 + lhi * 4;
#pragma unroll
            for (int i = 0; i < 4; i++) {
                float v = acc[m][n][i] + bv;
                if (B16OUT) ((u16*)Cv)[(size_t)(row + i) * N + col] = f2bf(v);
                else        ((float*)Cv)[(size_t)(row + i) * N + col] = v;
            }
        }
    }
}

// ---------------- RoPE + scatter (table-driven) ----------------
__global__ __launch_bounds__(256) void k_rope_scatter(
    const u16* __restrict__ qkv, const float2* __restrict__ tbl,
    u16* __restrict__ Qo, u16* __restrict__ Ko, u16* __restrict__ Vto) {
    int bt = blockIdx.x;
    int t = bt & (T_SEQ - 1), b = bt >> 11;
    const u16* row = qkv + (size_t)bt * 1536;
    const uint32_t* row32 = (const uint32_t*)row;
    __shared__ float cs[32], sn[32];
    int tid = threadIdx.x;
    if (tid < 32) {
        float2 p = tbl[t * 32 + tid];
        cs[tid] = p.x; sn[tid] = p.y;
    }
    __syncthreads();
    for (int j = tid; j < 512; j += 256) {
        int i = j & 31;
        uint32_t w = row32[j];
        float xe = bf2f((u16)w), xo = bf2f((u16)(w >> 16));
        float c = cs[i], s = sn[i];
        float re = (xe * c - xo * s) * QSCALE;
        float ro = (xe * s + xo * c) * QSCALE;
        int hq = j >> 5;
        size_t base = (((size_t)(b * NH + hq)) * T_SEQ + t) * DH + 2 * i;
        Qo[base] = f2bf(re); Qo[base + 1] = f2bf(ro);
    }
    if (tid < 128) {
        int g = tid >> 5, i = tid & 31;
        uint32_t w = row32[512 + tid];
        float xe = bf2f((u16)w), xo = bf2f((u16)(w >> 16));
        float c = cs[i], s = sn[i];
        float re = xe * c - xo * s;
        float ro = xe * s + xo * c;
        size_t base = (((size_t)(b * NG + g)) * T_SEQ + t) * DH + 2 * i;
        Ko[base] = f2bf(re); Ko[base + 1] = f2bf(ro);
    }
    {
        int g = tid >> 6, d = tid & 63;
        Vto[(((size_t)(b * NG + g)) * DH + d) * T_SEQ + t] = row[1280 + tid];
    }
}

// ---------------- causal GQA flash attention ----------------
// KVBLK=64 double-buffered; LDS = 40960B -> 4 blocks/CU.
// qt map: u<16 -> 31-u, else u-16  => each CU's 4 resident blocks (stride-256
// siblings) have constant total work; heavy tiles dispatch first.
// Steady-state iterations have ZERO cross-lane ops: rescale-check on
// per-thread partial max, l-reduce deferred to epilogue.
__global__ __launch_bounds__(256) void k_attn(
    const u16* __restrict__ Q, const u16* __restrict__ K,
    const u16* __restrict__ Vt, u16* __restrict__ Aout) {
    int i0 = blockIdx.x;
    int u = i0 >> 5;
    int qt = (u < 16) ? (31 - u) : (u - 16);
    int bh = i0 & 31;
    int b = bh >> 4, h = bh & 15, g = h >> 2;
    int tid = threadIdx.x;
    int lane = tid & 63, wid = tid >> 6;
    int l15 = lane & 15, lhi = lane >> 4;

    const u16* Kp = K + ((size_t)(b * NG + g)) * T_SEQ * DH;
    const u16* Vp = Vt + ((size_t)(b * NG + g)) * DH * T_SEQ;

    __shared__ __align__(16) u16 Ks[2][64 * 64];   // [s][d] swizzled, 8KB each
    __shared__ __align__(16) u16 Vs[2][64 * 64];   // [d][s] swizzled, 8KB each
    __shared__ __align__(16) u16 Ps[4][16 * 64];   // per-wave P, XOR-swizzled, 2KB each

    const u16* Qp = Q + ((size_t)bh * T_SEQ + qt * 64) * DH;
    bf16x8 qf[2];
#pragma unroll
    for (int ks = 0; ks < 2; ks++)
        qf[ks] = *(const bf16x8*)(Qp + (size_t)(wid * 16 + l15) * DH + ks * 32 + lhi * 8);

    f32x4 of[4] = {};
    float m_i[4] = {-3.0e38f, -3.0e38f, -3.0e38f, -3.0e38f};
    float l_i[4] = {0.f, 0.f, 0.f, 0.f};

    int nt = qt + 1;
    u16* Pw = Ps[wid];

    // staging addresses (chunk = 16B); advance by constant per iter
    int c0 = tid, c1 = tid + 256;
    int rk0 = c0 >> 3, sk0 = (c0 & 7) ^ (rk0 & 7);
    int rk1 = c1 >> 3, sk1 = (c1 & 7) ^ (rk1 & 7);
    const u16* kg0 = Kp + rk0 * DH + sk0 * 8;
    const u16* kg1 = Kp + rk1 * DH + sk1 * 8;
    const u16* vg0 = Vp + (size_t)rk0 * T_SEQ + sk0 * 8;
    const u16* vg1 = Vp + (size_t)rk1 * T_SEQ + sk1 * 8;

    // prologue: stage tile 0 into buf 0
    async16(kg0, &Ks[0][c0 * 8]);
    async16(kg1, &Ks[0][c1 * 8]);
    async16(vg0, &Vs[0][c0 * 8]);
    async16(vg1, &Vs[0][c1 * 8]);
    __syncthreads();

#pragma unroll 1
    for (int it = 0; it < nt; it++) {
        int cur = it & 1;
        if (it + 1 < nt) {   // issue next-tile loads; they fly under this iter's compute
            int nx = cur ^ 1;
            int ko = (it + 1) << 12;   // *64*64 elems
            int vo = (it + 1) << 6;    // *64 elems
            async16(kg0 + ko, &Ks[nx][c0 * 8]);
            async16(kg1 + ko, &Ks[nx][c1 * 8]);
            async16(vg0 + vo, &Vs[nx][c0 * 8]);
            async16(vg1 + vo, &Vs[nx][c1 * 8]);
        }
        const u16* Kc = Ks[cur];
        const u16* Vc = Vs[cur];

        // S = Q K^T (exp2 units)
        f32x4 sf[4] = {};
        __builtin_amdgcn_s_setprio(1);
#pragma unroll
        for (int ks = 0; ks < 2; ks++)
#pragma unroll
            for (int n = 0; n < 4; n++) {
                int sr = n * 16 + l15;
                int kb = (ks * 64 + lhi * 16) ^ ((sr & 7) << 4);
                bf16x8 kf = *(const bf16x8*)((const char*)Kc + sr * 128 + kb);
                sf[n] = __builtin_amdgcn_mfma_f32_16x16x32_bf16(qf[ks], kf, sf[n], 0, 0, 0);
            }
        __builtin_amdgcn_s_setprio(0);

        if (it == nt - 1) {   // diagonal tile: causal mask
            int qrow = qt * 64 + wid * 16 + lhi * 4;
            int sb = it * 64;
#pragma unroll
            for (int n = 0; n < 4; n++) {
                int sg = sb + n * 16 + l15;
#pragma unroll
                for (int i = 0; i < 4; i++)
                    if (sg > qrow + i) sf[n][i] = -3.0e38f;
            }
        }

        // per-thread partial max; full butterfly ONLY when rescale triggers
        float pmt[4];
#pragma unroll
        for (int i = 0; i < 4; i++)
            pmt[i] = fmaxf(fmaxf(sf[0][i], sf[1][i]), fmaxf(sf[2][i], sf[3][i]));
        int cond = (pmt[0] - m_i[0] <= 8.f) & (pmt[1] - m_i[1] <= 8.f) &
                   (pmt[2] - m_i[2] <= 8.f) & (pmt[3] - m_i[3] <= 8.f);
        if (!__all(cond)) {
#pragma unroll
            for (int off = 1; off <= 8; off <<= 1)
#pragma unroll
                for (int i = 0; i < 4; i++)
                    pmt[i] = fmaxf(pmt[i], __shfl_xor(pmt[i], off));
            float sc[4];
#pragma unroll
            for (int i = 0; i < 4; i++) {
                float mn = fmaxf(m_i[i], pmt[i]);
                sc[i] = fexp2(m_i[i] - mn);
                m_i[i] = mn;
                l_i[i] *= sc[i];
            }
#pragma unroll
            for (int n = 0; n < 4; n++)
#pragma unroll
                for (int i = 0; i < 4; i++)
                    of[n][i] *= sc[i];
        }
        // exp + per-thread partial row-sum (reduced once in epilogue)
#pragma unroll
        for (int n = 0; n < 4; n++)
#pragma unroll
            for (int i = 0; i < 4; i++) {
                float p = fexp2(sf[n][i] - m_i[i]);
                sf[n][i] = p;
                l_i[i] += p;
            }

        // P -> LDS (XOR-swizzled [16 q][64 s], no pad)
#pragma unroll
        for (int n = 0; n < 4; n++)
#pragma unroll
            for (int i = 0; i < 4; i++) {
                int q = lhi * 4 + i;
                int byte = q * 128 + ((((n << 1) | (l15 >> 3)) ^ (q & 7)) << 4) + ((l15 & 7) << 1);
                *(u16*)((char*)Pw + byte) = f2bf_rhu(sf[n][i]);
            }
        asm volatile("" ::: "memory");   // compile fence; per-wave LDS FIFO orders RAW

        // O += P V
        __builtin_amdgcn_s_setprio(1);
#pragma unroll
        for (int ks = 0; ks < 2; ks++) {
            bf16x8 pf = *(const bf16x8*)((const char*)Pw + l15 * 128 +
                                         ((((ks << 2) | lhi) ^ (l15 & 7)) << 4));
#pragma unroll
            for (int n = 0; n < 4; n++) {
                int dr = n * 16 + l15;
                int kb = (ks * 64 + lhi * 16) ^ ((dr & 7) << 4);
                bf16x8 vf = *(const bf16x8*)((const char*)Vc + dr * 128 + kb);
                of[n] = __builtin_amdgcn_mfma_f32_16x16x32_bf16(pf, vf, of[n], 0, 0, 0);
            }
        }
        __builtin_amdgcn_s_setprio(0);
        __syncthreads();   // next-tile loads drained here (flew under compute)
    }

    // epilogue: reduce per-thread partial l across the 16-lane row group
#pragma unroll
    for (int off = 1; off <= 8; off <<= 1)
#pragma unroll
        for (int i = 0; i < 4; i++)
            l_i[i] += __shfl_xor(l_i[i], off);
#pragma unroll
    for (int n = 0; n < 4; n++)
#pragma unroll
        for (int i = 0; i < 4; i++) {
            int trow = qt * 64 + wid * 16 + lhi * 4 + i;
            float v = of[n][i] / l_i[i];
            Aout[((size_t)(b * T_SEQ + trow)) * DM + h * 64 + n * 16 + l15] = f2bf(v);
        }
}

// ---------------- launch ----------------
extern "C" void kernel_launch(void* const* d_in, const int* in_sizes, int n_in,
                              void* d_out, int out_size, void* d_ws, size_t ws_size,
                              hipStream_t stream) {
    const float* x  = (const float*)d_in[0];
    const float* Wq = (const float*)d_in[1];
    const float* bq = (const float*)d_in[2];
    const float* Wk = (const float*)d_in[3];
    const float* bk = (const float*)d_in[4];
    const float* Wv = (const float*)d_in[5];
    const float* bv = (const float*)d_in[6];
    const float* Wo = (const float*)d_in[7];
    const float* bo = (const float*)d_in[8];

    char* ws = (char*)d_ws;
    size_t o = 0;
    u16*   xb    = (u16*)(ws + o);  o += (size_t)4096 * 1024 * 2;
    u16*   wqkvt = (u16*)(ws + o);  o += (size_t)1536 * 1024 * 2;
    u16*   wot   = (u16*)(ws + o);  o += (size_t)1024 * 1024 * 2;
    float* bqkv  = (float*)(ws + o); o += 1536 * 4;
    o = (o + 255) & ~(size_t)255;
    u16*   qkvt  = (u16*)(ws + o);  o += (size_t)4096 * 1536 * 2;
    u16*   Qb    = (u16*)(ws + o);  o += (size_t)2 * NH * T_SEQ * DH * 2;
    u16*   Kb    = (u16*)(ws + o);  o += (size_t)2 * NG * T_SEQ * DH * 2;
    u16*   Vtb   = (u16*)(ws + o);  o += (size_t)2 * NG * DH * T_SEQ * 2;
    u16*   attnb = (u16*)(ws + o);  o += (size_t)4096 * 1024 * 2;
    float2* tbl  = (float2*)(ws + o); o += (size_t)2048 * 32 * 8;

    k_prep<<<4870, 256, 0, stream>>>(x, xb, Wq, Wk, Wv, Wo, wqkvt, wot, bq, bk, bv, bqkv, tbl);
    k_gemm_bt<1><<<dim3(12, 64), 256, 0, stream>>>(xb, wqkvt, bqkv, qkvt, 4096, 1536, 1024);
    k_rope_scatter<<<4096, 256, 0, stream>>>(qkvt, tbl, Qb, Kb, Vtb);
    k_attn<<<1024, 256, 0, stream>>>(Qb, Kb, Vtb, attnb);
    k_gemm_bt<0><<<dim3(8, 64), 256, 0, stream>>>(attnb, wot, bo, d_out, 4096, 1024, 1024);
}

// Round 6
// 101.525 us; speedup vs baseline: 1.8290x; 1.0387x over previous
//
#include <hip/hip_runtime.h>
#include <stdint.h>

typedef unsigned short u16;
typedef __attribute__((ext_vector_type(4))) float f32x4;
typedef __attribute__((ext_vector_type(8))) short bf16x8;
typedef __attribute__((ext_vector_type(4))) short bf16x4;

#define T_SEQ 2048
#define DM 1024
#define NH 16
#define NG 4
#define DH 64
// 0.125 (1/sqrt(64)) * log2(e): softmax computed in exp2 units
#define QSCALE 0.18033688011112042f

__device__ __forceinline__ u16 f2bf(float f) {
    union { float f; uint32_t u; } v; v.f = f;
    uint32_t r = (v.u + 0x7FFFu + ((v.u >> 16) & 1u)) >> 16;
    return (u16)r;
}
__device__ __forceinline__ float bf2f(u16 u) {
    union { uint32_t u; float f; } v; v.u = ((uint32_t)u) << 16;
    return v.f;
}
__device__ __forceinline__ float fexp2(float x) {
#if __has_builtin(__builtin_amdgcn_exp2f)
    return __builtin_amdgcn_exp2f(x);
#else
    return exp2f(x);
#endif
}
__device__ __forceinline__ uint32_t cvtpk_bf16(float a, float b) {
    uint32_t r;
    asm("v_cvt_pk_bf16_f32 %0, %1, %2" : "=v"(r) : "v"(a), "v"(b));
    return r;
}

// K=16 bf16 MFMA (A/B: 4 bf16/lane, row|col=lane&15, k=(lane>>4)*4+j)
#if __has_builtin(__builtin_amdgcn_mfma_f32_16x16x16_bf16)
__device__ __forceinline__ f32x4 mfma16(bf16x4 a, bf16x4 b, f32x4 c) {
    return __builtin_amdgcn_mfma_f32_16x16x16_bf16(a, b, c, 0, 0, 0);
}
#elif __has_builtin(__builtin_amdgcn_mfma_f32_16x16x16bf16_1k)
__device__ __forceinline__ f32x4 mfma16(bf16x4 a, bf16x4 b, f32x4 c) {
    return __builtin_amdgcn_mfma_f32_16x16x16bf16_1k(a, b, c, 0, 0, 0);
}
#else
__device__ __forceinline__ f32x4 mfma16(bf16x4 a, bf16x4 b, f32x4 c) {
    asm("v_mfma_f32_16x16x16_bf16 %0, %1, %2, %0" : "+v"(c) : "v"(a), "v"(b));
    return c;
}
#endif

__device__ __forceinline__ void async16(const void* g, void* l) {
    __builtin_amdgcn_global_load_lds(
        (const __attribute__((address_space(1))) void*)g,
        (__attribute__((address_space(3))) void*)l,
        16, 0, 0);
}

// ---------------- fused prep: cast x, transpose 4 weights, bias concat, trig table ----------------
__global__ __launch_bounds__(256) void k_prep(
    const float* __restrict__ x, u16* __restrict__ xb,
    const float* __restrict__ Wq, const float* __restrict__ Wk,
    const float* __restrict__ Wv, const float* __restrict__ Wo,
    u16* __restrict__ wqkvt, u16* __restrict__ wot,
    const float* __restrict__ bq, const float* __restrict__ bk,
    const float* __restrict__ bv, float* __restrict__ bqkv,
    float2* __restrict__ tbl) {
    int blk = blockIdx.x;
    int tid = threadIdx.x;
    if (blk < 2048) {  // cast x -> bf16, 8 elems/thread
        int i = blk * 256 + tid;
        const float4* p = (const float4*)x + (size_t)i * 2;
        float4 a = p[0], b = p[1];
        bf16x8 v;
        v[0] = (short)f2bf(a.x); v[1] = (short)f2bf(a.y);
        v[2] = (short)f2bf(a.z); v[3] = (short)f2bf(a.w);
        v[4] = (short)f2bf(b.x); v[5] = (short)f2bf(b.y);
        v[6] = (short)f2bf(b.z); v[7] = (short)f2bf(b.w);
        ((bf16x8*)xb)[i] = v;
        return;
    }
    int t = blk - 2048;
    if (t >= 2560) {
        int u = t - 2560;
        if (u < 6) {  // bias concat
            int i = u * 256 + tid;
            if (i < 1536) {
                float v;
                if (i < 1024) v = bq[i];
                else if (i < 1280) v = bk[i - 1024];
                else v = bv[i - 1280];
                bqkv[i] = v;
            }
        } else {      // trig table: [2048 t][32 i] -> (cos, sin)
            int idx = (u - 6) * 256 + tid;
            int tt = idx >> 5, i = idx & 31;
            float freq = exp2f(-(float)i * (13.287712379549449f / 32.0f));
            float ang = (float)tt * freq;
            tbl[idx] = make_float2(cosf(ang), sinf(ang));
        }
        return;
    }
    const float* src; u16* dst; int N;
    if (t < 1024)      { src = Wq; dst = wqkvt;                      N = 1024; }
    else if (t < 1280) { t -= 1024; src = Wk; dst = wqkvt + (size_t)1024 * 1024; N = 256; }
    else if (t < 1536) { t -= 1280; src = Wv; dst = wqkvt + (size_t)1280 * 1024; N = 256; }
    else               { t -= 1536; src = Wo; dst = wot;             N = 1024; }
    int ntiles = N >> 5;
    int n0 = (t % ntiles) * 32, k0 = (t / ntiles) * 32;
    __shared__ float tile[32][33];
    int tx = tid & 31, ty = tid >> 5;
#pragma unroll
    for (int q = 0; q < 4; q++)
        tile[ty + q * 8][tx] = src[(size_t)(k0 + ty + q * 8) * N + n0 + tx];
    __syncthreads();
#pragma unroll
    for (int q = 0; q < 4; q++)
        dst[(size_t)(n0 + ty + q * 8) * 1024 + k0 + tx] = f2bf(tile[tx][ty + q * 8]);
}

// ---------------- GEMM 64x128 tile: C[M][N] = A[M][K](bf16) @ Bt[N][K]^T + bias ----------------
template <int B16OUT>
__global__ __launch_bounds__(256) void k_gemm_bt(
    const u16* __restrict__ A, const u16* __restrict__ Bt,
    const float* __restrict__ bias, void* __restrict__ Cv,
    int M, int N, int K) {
    __shared__ __align__(16) u16 As[64 * 64];
    __shared__ __align__(16) u16 Bs[128 * 64];
    int tid = threadIdx.x;
    int lane = tid & 63, wid = tid >> 6;
    int wr = wid >> 1, wc = wid & 1;
    int l15 = lane & 15, lhi = lane >> 4;
    int row0 = blockIdx.y * 64, col0 = blockIdx.x * 128;
    f32x4 acc[2][4] = {};

    for (int k0 = 0; k0 < K; k0 += 64) {
#pragma unroll
        for (int i = 0; i < 2; i++) {
            int c = i * 256 + tid;
            int r = c >> 3, ch = c & 7;
            int sch = ch ^ (r & 7);
            async16(A + (size_t)(row0 + r) * K + k0 + sch * 8, &As[c * 8]);
        }
#pragma unroll
        for (int i = 0; i < 4; i++) {
            int c = i * 256 + tid;
            int r = c >> 3, ch = c & 7;
            int sch = ch ^ (r & 7);
            async16(Bt + (size_t)(col0 + r) * K + k0 + sch * 8, &Bs[c * 8]);
        }
        __syncthreads();
#pragma unroll
        for (int ks = 0; ks < 2; ks++) {
            bf16x8 af[2], bfr[4];
#pragma unroll
            for (int m = 0; m < 2; m++) {
                int r = wr * 32 + m * 16 + l15;
                int kb = (ks * 64 + lhi * 16) ^ ((r & 7) << 4);
                af[m] = *(const bf16x8*)((const char*)As + r * 128 + kb);
            }
#pragma unroll
            for (int n = 0; n < 4; n++) {
                int r = wc * 64 + n * 16 + l15;
                int kb = (ks * 64 + lhi * 16) ^ ((r & 7) << 4);
                bfr[n] = *(const bf16x8*)((const char*)Bs + r * 128 + kb);
            }
#pragma unroll
            for (int m = 0; m < 2; m++)
#pragma unroll
                for (int n = 0; n < 4; n++)
                    acc[m][n] = __builtin_amdgcn_mfma_f32_16x16x32_bf16(
                        af[m], bfr[n], acc[m][n], 0, 0, 0);
        }
        __syncthreads();
    }
#pragma unroll
    for (int n = 0; n < 4; n++) {
        int col = col0 + wc * 64 + n * 16 + l15;
        float bv = bias[col];
#pragma unroll
        for (int m = 0; m < 2; m++) {
            int row = row0 + wr * 32 + m * 16 + lhi * 4;
#pragma unroll
            for (int i = 0; i < 4; i++) {
                float v = acc[m][n][i] + bv;
                if (B16OUT) ((u16*)Cv)[(size_t)(row + i) * N + col] = f2bf(v);
                else        ((float*)Cv)[(size_t)(row + i) * N + col] = v;
            }
        }
    }
}

// ---------------- RoPE + scatter (table-driven) ----------------
__global__ __launch_bounds__(256) void k_rope_scatter(
    const u16* __restrict__ qkv, const float2* __restrict__ tbl,
    u16* __restrict__ Qo, u16* __restrict__ Ko, u16* __restrict__ Vto) {
    int bt = blockIdx.x;
    int t = bt & (T_SEQ - 1), b = bt >> 11;
    const u16* row = qkv + (size_t)bt * 1536;
    const uint32_t* row32 = (const uint32_t*)row;
    __shared__ float cs[32], sn[32];
    int tid = threadIdx.x;
    if (tid < 32) {
        float2 p = tbl[t * 32 + tid];
        cs[tid] = p.x; sn[tid] = p.y;
    }
    __syncthreads();
    for (int j = tid; j < 512; j += 256) {
        int i = j & 31;
        uint32_t w = row32[j];
        float xe = bf2f((u16)w), xo = bf2f((u16)(w >> 16));
        float c = cs[i], s = sn[i];
        float re = (xe * c - xo * s) * QSCALE;
        float ro = (xe * s + xo * c) * QSCALE;
        int hq = j >> 5;
        size_t base = (((size_t)(b * NH + hq)) * T_SEQ + t) * DH + 2 * i;
        Qo[base] = f2bf(re); Qo[base + 1] = f2bf(ro);
    }
    if (tid < 128) {
        int g = tid >> 5, i = tid & 31;
        uint32_t w = row32[512 + tid];
        float xe = bf2f((u16)w), xo = bf2f((u16)(w >> 16));
        float c = cs[i], s = sn[i];
        float re = xe * c - xo * s;
        float ro = xe * s + xo * c;
        size_t base = (((size_t)(b * NG + g)) * T_SEQ + t) * DH + 2 * i;
        Ko[base] = f2bf(re); Ko[base + 1] = f2bf(ro);
    }
    {
        int g = tid >> 6, d = tid & 63;
        Vto[(((size_t)(b * NG + g)) * DH + d) * T_SEQ + t] = row[1280 + tid];
    }
}

// ---------------- causal GQA flash attention ----------------
// Swapped QK^T (S^T fragments): thread owns ONE q-row (q = wid*16+l15),
// 16 P-values at s = n*16 + lhi*4 + i. This layout IS the A-fragment of
// v_mfma_f32_16x16x16_bf16 (k = lhi*4+j), so PV runs entirely in-register:
// no P LDS, no shuffles. m/l are per-thread scalars; l-reduce deferred.
// LDS = 32768 B (K/V dbuf only) -> 4+ blocks/CU.
__global__ __launch_bounds__(256) void k_attn(
    const u16* __restrict__ Q, const u16* __restrict__ K,
    const u16* __restrict__ Vt, u16* __restrict__ Aout) {
    int i0 = blockIdx.x;
    int u = i0 >> 5;
    int qt = (u < 16) ? (31 - u) : (u - 16);   // CU-sibling work sums constant
    int bh = i0 & 31;
    int b = bh >> 4, h = bh & 15, g = h >> 2;
    int tid = threadIdx.x;
    int lane = tid & 63, wid = tid >> 6;
    int l15 = lane & 15, lhi = lane >> 4;

    const u16* Kp = K + ((size_t)(b * NG + g)) * T_SEQ * DH;
    const u16* Vp = Vt + ((size_t)(b * NG + g)) * DH * T_SEQ;

    __shared__ __align__(16) u16 Ks[2][64 * 64];   // [s][d] swizzled, 8KB each
    __shared__ __align__(16) u16 Vs[2][64 * 64];   // [d][s] swizzled, 8KB each

    const u16* Qp = Q + ((size_t)bh * T_SEQ + qt * 64) * DH;
    bf16x8 qf[2];   // B-operand: col=q=wid*16+l15, k=d=ks*32+lhi*8+j
#pragma unroll
    for (int ks = 0; ks < 2; ks++)
        qf[ks] = *(const bf16x8*)(Qp + (size_t)(wid * 16 + l15) * DH + ks * 32 + lhi * 8);

    f32x4 of[4] = {};
    float m_i = -3.0e38f, l_i = 0.f;

    int nt = qt + 1;
    int swz = (l15 & 7) << 4;   // row-XOR swizzle term (row&7 == l15&7 for all reads)

    // staging addresses (chunk = 16B); advance by constant per iter
    int c0 = tid, c1 = tid + 256;
    int rk0 = c0 >> 3, sk0 = (c0 & 7) ^ (rk0 & 7);
    int rk1 = c1 >> 3, sk1 = (c1 & 7) ^ (rk1 & 7);
    const u16* kg0 = Kp + rk0 * DH + sk0 * 8;
    const u16* kg1 = Kp + rk1 * DH + sk1 * 8;
    const u16* vg0 = Vp + (size_t)rk0 * T_SEQ + sk0 * 8;
    const u16* vg1 = Vp + (size_t)rk1 * T_SEQ + sk1 * 8;

    // prologue: stage tile 0 into buf 0
    async16(kg0, &Ks[0][c0 * 8]);
    async16(kg1, &Ks[0][c1 * 8]);
    async16(vg0, &Vs[0][c0 * 8]);
    async16(vg1, &Vs[0][c1 * 8]);
    __syncthreads();

#pragma unroll 1
    for (int it = 0; it < nt; it++) {
        int cur = it & 1;
        if (it + 1 < nt) {   // next-tile loads fly under this iter's compute
            int nx = cur ^ 1;
            int ko = (it + 1) << 12;   // *64*64 elems
            int vo = (it + 1) << 6;    // *64 elems
            async16(kg0 + ko, &Ks[nx][c0 * 8]);
            async16(kg1 + ko, &Ks[nx][c1 * 8]);
            async16(vg0 + vo, &Vs[nx][c0 * 8]);
            async16(vg1 + vo, &Vs[nx][c1 * 8]);
        }
        const u16* Kc = Ks[cur];
        const u16* Vc = Vs[cur];

        // S^T = K Q^T (exp2 units): sf[n][i] = S[s=n*16+lhi*4+i][q=wid*16+l15]
        f32x4 sf[4] = {};
        __builtin_amdgcn_s_setprio(1);
#pragma unroll
        for (int ks = 0; ks < 2; ks++)
#pragma unroll
            for (int n = 0; n < 4; n++) {
                int kb = (ks * 64 + lhi * 16) ^ swz;
                bf16x8 kf = *(const bf16x8*)((const char*)Kc + (n * 16 + l15) * 128 + kb);
                sf[n] = __builtin_amdgcn_mfma_f32_16x16x32_bf16(kf, qf[ks], sf[n], 0, 0, 0);
            }
        __builtin_amdgcn_s_setprio(0);

        if (it == nt - 1) {   // diagonal tile: causal mask (s > q)
            int qrow = qt * 64 + wid * 16 + l15;
            int sb = it * 64 + lhi * 4;
#pragma unroll
            for (int n = 0; n < 4; n++)
#pragma unroll
                for (int i = 0; i < 4; i++)
                    if (sb + n * 16 + i > qrow) sf[n][i] = -3.0e38f;
        }

        // per-thread partial max over this thread's 16 s-values (one q-row)
        float pmt = sf[0][0];
#pragma unroll
        for (int n = 0; n < 4; n++)
#pragma unroll
            for (int i = 0; i < 4; i++)
                pmt = fmaxf(pmt, sf[n][i]);
        if (!__all(pmt - m_i <= 8.f)) {   // rare: rescale path
#pragma unroll
            for (int off = 16; off <= 32; off <<= 1)
                pmt = fmaxf(pmt, __shfl_xor(pmt, off));   // row-max (4 lanes)
            float mn = fmaxf(m_i, pmt);
            float sc = fexp2(m_i - mn);
            m_i = mn;
            l_i *= sc;
            float sc4[4];
#pragma unroll
            for (int i = 0; i < 4; i++)
                sc4[i] = __shfl(sc, lhi * 4 + i);   // sc for output rows q=wid*16+lhi*4+i
#pragma unroll
            for (int n = 0; n < 4; n++)
#pragma unroll
                for (int i = 0; i < 4; i++)
                    of[n][i] *= sc4[i];
        }
        // exp + per-thread partial row-sum; pack P to bf16 A-fragments
        bf16x4 pa[4];
#pragma unroll
        for (int n = 0; n < 4; n++) {
#pragma unroll
            for (int i = 0; i < 4; i++) {
                float p = fexp2(sf[n][i] - m_i);
                sf[n][i] = p;
                l_i += p;
            }
            union { uint32_t u[2]; bf16x4 v; } pu;
            pu.u[0] = cvtpk_bf16(sf[n][0], sf[n][1]);
            pu.u[1] = cvtpk_bf16(sf[n][2], sf[n][3]);
            pa[n] = pu.v;
        }

        // O += P V : 16x16x16 MFMAs, A=pa (in-register), B=V^T b64 from LDS
        __builtin_amdgcn_s_setprio(1);
#pragma unroll
        for (int nd = 0; nd < 4; nd++) {
            int rowb = (nd * 16 + l15) * 128 + ((lhi & 1) << 3);
#pragma unroll
            for (int n = 0; n < 4; n++) {
                int cg = 2 * n + (lhi >> 1);              // global 16B chunk of s-offset
                int kb = ((cg << 4) ^ swz);
                bf16x4 vf = *(const bf16x4*)((const char*)Vc + rowb + kb);
                of[nd] = mfma16(pa[n], vf, of[nd]);
            }
        }
        __builtin_amdgcn_s_setprio(0);
        __syncthreads();   // next-tile loads drained here (flew under compute)
    }

    // epilogue: row-sum = reduce partials over the 4 lhi lanes, then fetch
    // the sums for output rows q = wid*16 + lhi*4 + i
#pragma unroll
    for (int off = 16; off <= 32; off <<= 1)
        l_i += __shfl_xor(l_i, off);
    float lq[4];
#pragma unroll
    for (int i = 0; i < 4; i++)
        lq[i] = __shfl(l_i, lhi * 4 + i);
#pragma unroll
    for (int n = 0; n < 4; n++)
#pragma unroll
        for (int i = 0; i < 4; i++) {
            int trow = qt * 64 + wid * 16 + lhi * 4 + i;
            float v = of[n][i] / lq[i];
            Aout[((size_t)(b * T_SEQ + trow)) * DM + h * 64 + n * 16 + l15] = f2bf(v);
        }
}

// ---------------- launch ----------------
extern "C" void kernel_launch(void* const* d_in, const int* in_sizes, int n_in,
                              void* d_out, int out_size, void* d_ws, size_t ws_size,
                              hipStream_t stream) {
    const float* x  = (const float*)d_in[0];
    const float* Wq = (const float*)d_in[1];
    const float* bq = (const float*)d_in[2];
    const float* Wk = (const float*)d_in[3];
    const float* bk = (const float*)d_in[4];
    const float* Wv = (const float*)d_in[5];
    const float* bv = (const float*)d_in[6];
    const float* Wo = (const float*)d_in[7];
    const float* bo = (const float*)d_in[8];

    char* ws = (char*)d_ws;
    size_t o = 0;
    u16*   xb    = (u16*)(ws + o);  o += (size_t)4096 * 1024 * 2;
    u16*   wqkvt = (u16*)(ws + o);  o += (size_t)1536 * 1024 * 2;
    u16*   wot   = (u16*)(ws + o);  o += (size_t)1024 * 1024 * 2;
    float* bqkv  = (float*)(ws + o); o += 1536 * 4;
    o = (o + 255) & ~(size_t)255;
    u16*   qkvt  = (u16*)(ws + o);  o += (size_t)4096 * 1536 * 2;
    u16*   Qb    = (u16*)(ws + o);  o += (size_t)2 * NH * T_SEQ * DH * 2;
    u16*   Kb    = (u16*)(ws + o);  o += (size_t)2 * NG * T_SEQ * DH * 2;
    u16*   Vtb   = (u16*)(ws + o);  o += (size_t)2 * NG * DH * T_SEQ * 2;
    u16*   attnb = (u16*)(ws + o);  o += (size_t)4096 * 1024 * 2;
    float2* tbl  = (float2*)(ws + o); o += (size_t)2048 * 32 * 8;

    k_prep<<<4870, 256, 0, stream>>>(x, xb, Wq, Wk, Wv, Wo, wqkvt, wot, bq, bk, bv, bqkv, tbl);
    k_gemm_bt<1><<<dim3(12, 64), 256, 0, stream>>>(xb, wqkvt, bqkv, qkvt, 4096, 1536, 1024);
    k_rope_scatter<<<4096, 256, 0, stream>>>(qkvt, tbl, Qb, Kb, Vtb);
    k_attn<<<1024, 256, 0, stream>>>(Qb, Kb, Vtb, attnb);
    k_gemm_bt<0><<<dim3(8, 64), 256, 0, stream>>>(attnb, wot, bo, d_out, 4096, 1024, 1024);
}

// Round 7
// 91.298 us; speedup vs baseline: 2.0339x; 1.1120x over previous
//
#include <hip/hip_runtime.h>
#include <stdint.h>

typedef unsigned short u16;
typedef __attribute__((ext_vector_type(4))) float f32x4;
typedef __attribute__((ext_vector_type(8))) short bf16x8;
typedef __attribute__((ext_vector_type(4))) short bf16x4;

#define T_SEQ 2048
#define DM 1024
#define NH 16
#define NG 4
#define DH 64
// 0.125 (1/sqrt(64)) * log2(e): softmax computed in exp2 units
#define QSCALE 0.18033688011112042f

__device__ __forceinline__ u16 f2bf(float f) {
    union { float f; uint32_t u; } v; v.f = f;
    uint32_t r = (v.u + 0x7FFFu + ((v.u >> 16) & 1u)) >> 16;
    return (u16)r;
}
__device__ __forceinline__ float bf2f(u16 u) {
    union { uint32_t u; float f; } v; v.u = ((uint32_t)u) << 16;
    return v.f;
}
__device__ __forceinline__ float fexp2(float x) {
#if __has_builtin(__builtin_amdgcn_exp2f)
    return __builtin_amdgcn_exp2f(x);
#else
    return exp2f(x);
#endif
}
__device__ __forceinline__ uint32_t cvtpk_bf16(float a, float b) {
    uint32_t r;
    asm("v_cvt_pk_bf16_f32 %0, %1, %2" : "=v"(r) : "v"(a), "v"(b));
    return r;
}

// K=16 bf16 MFMA (A/B: 4 bf16/lane, row|col=lane&15, k=(lane>>4)*4+j)
#if __has_builtin(__builtin_amdgcn_mfma_f32_16x16x16_bf16)
__device__ __forceinline__ f32x4 mfma16(bf16x4 a, bf16x4 b, f32x4 c) {
    return __builtin_amdgcn_mfma_f32_16x16x16_bf16(a, b, c, 0, 0, 0);
}
#elif __has_builtin(__builtin_amdgcn_mfma_f32_16x16x16bf16_1k)
__device__ __forceinline__ f32x4 mfma16(bf16x4 a, bf16x4 b, f32x4 c) {
    return __builtin_amdgcn_mfma_f32_16x16x16bf16_1k(a, b, c, 0, 0, 0);
}
#else
__device__ __forceinline__ f32x4 mfma16(bf16x4 a, bf16x4 b, f32x4 c) {
    asm("v_mfma_f32_16x16x16_bf16 %0, %1, %2, %0" : "+v"(c) : "v"(a), "v"(b));
    return c;
}
#endif

__device__ __forceinline__ void async16(const void* g, void* l) {
    __builtin_amdgcn_global_load_lds(
        (const __attribute__((address_space(1))) void*)g,
        (__attribute__((address_space(3))) void*)l,
        16, 0, 0);
}

// ---------------- fused prep: cast x, transpose 4 weights, bias concat, trig table ----------------
__global__ __launch_bounds__(256) void k_prep(
    const float* __restrict__ x, u16* __restrict__ xb,
    const float* __restrict__ Wq, const float* __restrict__ Wk,
    const float* __restrict__ Wv, const float* __restrict__ Wo,
    u16* __restrict__ wqkvt, u16* __restrict__ wot,
    const float* __restrict__ bq, const float* __restrict__ bk,
    const float* __restrict__ bv, float* __restrict__ bqkv,
    float2* __restrict__ tbl) {
    int blk = blockIdx.x;
    int tid = threadIdx.x;
    if (blk < 2048) {  // cast x -> bf16, 8 elems/thread
        int i = blk * 256 + tid;
        const float4* p = (const float4*)x + (size_t)i * 2;
        float4 a = p[0], b = p[1];
        bf16x8 v;
        v[0] = (short)f2bf(a.x); v[1] = (short)f2bf(a.y);
        v[2] = (short)f2bf(a.z); v[3] = (short)f2bf(a.w);
        v[4] = (short)f2bf(b.x); v[5] = (short)f2bf(b.y);
        v[6] = (short)f2bf(b.z); v[7] = (short)f2bf(b.w);
        ((bf16x8*)xb)[i] = v;
        return;
    }
    int t = blk - 2048;
    if (t >= 2560) {
        int u = t - 2560;
        if (u < 6) {  // bias concat
            int i = u * 256 + tid;
            if (i < 1536) {
                float v;
                if (i < 1024) v = bq[i];
                else if (i < 1280) v = bk[i - 1024];
                else v = bv[i - 1280];
                bqkv[i] = v;
            }
        } else {      // trig table: [2048 t][32 i] -> (cos, sin)
            int idx = (u - 6) * 256 + tid;
            int tt = idx >> 5, i = idx & 31;
            float freq = exp2f(-(float)i * (13.287712379549449f / 32.0f));
            float ang = (float)tt * freq;
            tbl[idx] = make_float2(cosf(ang), sinf(ang));
        }
        return;
    }
    const float* src; u16* dst; int N;
    if (t < 1024)      { src = Wq; dst = wqkvt;                      N = 1024; }
    else if (t < 1280) { t -= 1024; src = Wk; dst = wqkvt + (size_t)1024 * 1024; N = 256; }
    else if (t < 1536) { t -= 1280; src = Wv; dst = wqkvt + (size_t)1280 * 1024; N = 256; }
    else               { t -= 1536; src = Wo; dst = wot;             N = 1024; }
    int ntiles = N >> 5;
    int n0 = (t % ntiles) * 32, k0 = (t / ntiles) * 32;
    __shared__ float tile[32][33];
    int tx = tid & 31, ty = tid >> 5;
#pragma unroll
    for (int q = 0; q < 4; q++)
        tile[ty + q * 8][tx] = src[(size_t)(k0 + ty + q * 8) * N + n0 + tx];
    __syncthreads();
#pragma unroll
    for (int q = 0; q < 4; q++)
        dst[(size_t)(n0 + ty + q * 8) * 1024 + k0 + tx] = f2bf(tile[tx][ty + q * 8]);
}

// ---------------- QKV GEMM 64x128 + fused bias/RoPE/scatter epilogue ----------------
// C = xb[4096][1024] @ wqkvt[1536][1024]^T; tiles: col0<1024 Q | <1280 K | else V.
// Q/K: RoPE via shfl_xor(1) column pairing; Q scaled by QSCALE.
// V: transposed store Vt[b][g][d][s^((d&1)<<2)] (8B-half swizzle baked in global).
__global__ __launch_bounds__(256) void k_gemm_qkv(
    const u16* __restrict__ A, const u16* __restrict__ Bt,
    const float* __restrict__ bias, const float2* __restrict__ tbl,
    u16* __restrict__ Qo, u16* __restrict__ Ko, u16* __restrict__ Vto) {
    const int K = 1024;
    __shared__ __align__(16) u16 As[64 * 64];
    __shared__ __align__(16) u16 Bs[128 * 64];
    int tid = threadIdx.x;
    int lane = tid & 63, wid = tid >> 6;
    int wr = wid >> 1, wc = wid & 1;
    int l15 = lane & 15, lhi = lane >> 4;
    int row0 = blockIdx.y * 64, col0 = blockIdx.x * 128;
    f32x4 acc[2][4] = {};

    for (int k0 = 0; k0 < K; k0 += 64) {
#pragma unroll
        for (int i = 0; i < 2; i++) {
            int c = i * 256 + tid;
            int r = c >> 3, ch = c & 7;
            int sch = ch ^ (r & 7);
            async16(A + (size_t)(row0 + r) * K + k0 + sch * 8, &As[c * 8]);
        }
#pragma unroll
        for (int i = 0; i < 4; i++) {
            int c = i * 256 + tid;
            int r = c >> 3, ch = c & 7;
            int sch = ch ^ (r & 7);
            async16(Bt + (size_t)(col0 + r) * K + k0 + sch * 8, &Bs[c * 8]);
        }
        __syncthreads();
#pragma unroll
        for (int ks = 0; ks < 2; ks++) {
            bf16x8 af[2], bfr[4];
#pragma unroll
            for (int m = 0; m < 2; m++) {
                int r = wr * 32 + m * 16 + l15;
                int kb = (ks * 64 + lhi * 16) ^ ((r & 7) << 4);
                af[m] = *(const bf16x8*)((const char*)As + r * 128 + kb);
            }
#pragma unroll
            for (int n = 0; n < 4; n++) {
                int r = wc * 64 + n * 16 + l15;
                int kb = (ks * 64 + lhi * 16) ^ ((r & 7) << 4);
                bfr[n] = *(const bf16x8*)((const char*)Bs + r * 128 + kb);
            }
#pragma unroll
            for (int m = 0; m < 2; m++)
#pragma unroll
                for (int n = 0; n < 4; n++)
                    acc[m][n] = __builtin_amdgcn_mfma_f32_16x16x32_bf16(
                        af[m], bfr[n], acc[m][n], 0, 0, 0);
        }
        __syncthreads();
    }

    // fused epilogue
    int type = (col0 >= 1280) ? 2 : (col0 >= 1024 ? 1 : 0);   // block-uniform
    int rbase = row0 + wr * 32;
#pragma unroll
    for (int n = 0; n < 4; n++) {
        int col = col0 + wc * 64 + n * 16 + l15;
        float bv = bias[col];
        if (type == 2) {          // V: transposed + 8B-half swizzled store
            int cc = col - 1280;
            int g = cc >> 6, d = cc & 63;
#pragma unroll
            for (int m = 0; m < 2; m++)
#pragma unroll
                for (int i = 0; i < 4; i++) {
                    int rowg = rbase + m * 16 + lhi * 4 + i;
                    int t = rowg & (T_SEQ - 1), b = rowg >> 11;
                    int sp = t ^ ((d & 1) << 2);
                    Vto[(((size_t)(b * NG + g)) * DH + d) * T_SEQ + sp] =
                        f2bf(acc[m][n][i] + bv);
                }
        } else {                  // Q or K: RoPE
            float ssgn = (col & 1) ? 1.f : -1.f;
            int ip = (col & 63) >> 1;
#pragma unroll
            for (int m = 0; m < 2; m++)
#pragma unroll
                for (int i = 0; i < 4; i++) {
                    int rowg = rbase + m * 16 + lhi * 4 + i;
                    int t = rowg & (T_SEQ - 1), b = rowg >> 11;
                    float v = acc[m][n][i] + bv;
                    float other = __shfl_xor(v, 1);   // partner column (same row)
                    float2 cs = tbl[t * 32 + ip];
                    float out = v * cs.x + other * cs.y * ssgn;
                    if (type == 0) {
                        int h = col >> 6, d = col & 63;
                        Qo[(((size_t)(b * NH + h)) * T_SEQ + t) * DH + d] =
                            f2bf(out * QSCALE);
                    } else {
                        int cc = col - 1024;
                        int g = cc >> 6, d = cc & 63;
                        Ko[(((size_t)(b * NG + g)) * T_SEQ + t) * DH + d] = f2bf(out);
                    }
                }
        }
    }
}

// ---------------- out-proj GEMM 64x128: C f32 = A bf16 @ Bt^T + bias ----------------
__global__ __launch_bounds__(256) void k_gemm_out(
    const u16* __restrict__ A, const u16* __restrict__ Bt,
    const float* __restrict__ bias, float* __restrict__ C,
    int M, int N, int K) {
    __shared__ __align__(16) u16 As[64 * 64];
    __shared__ __align__(16) u16 Bs[128 * 64];
    int tid = threadIdx.x;
    int lane = tid & 63, wid = tid >> 6;
    int wr = wid >> 1, wc = wid & 1;
    int l15 = lane & 15, lhi = lane >> 4;
    int row0 = blockIdx.y * 64, col0 = blockIdx.x * 128;
    f32x4 acc[2][4] = {};

    for (int k0 = 0; k0 < K; k0 += 64) {
#pragma unroll
        for (int i = 0; i < 2; i++) {
            int c = i * 256 + tid;
            int r = c >> 3, ch = c & 7;
            int sch = ch ^ (r & 7);
            async16(A + (size_t)(row0 + r) * K + k0 + sch * 8, &As[c * 8]);
        }
#pragma unroll
        for (int i = 0; i < 4; i++) {
            int c = i * 256 + tid;
            int r = c >> 3, ch = c & 7;
            int sch = ch ^ (r & 7);
            async16(Bt + (size_t)(col0 + r) * K + k0 + sch * 8, &Bs[c * 8]);
        }
        __syncthreads();
#pragma unroll
        for (int ks = 0; ks < 2; ks++) {
            bf16x8 af[2], bfr[4];
#pragma unroll
            for (int m = 0; m < 2; m++) {
                int r = wr * 32 + m * 16 + l15;
                int kb = (ks * 64 + lhi * 16) ^ ((r & 7) << 4);
                af[m] = *(const bf16x8*)((const char*)As + r * 128 + kb);
            }
#pragma unroll
            for (int n = 0; n < 4; n++) {
                int r = wc * 64 + n * 16 + l15;
                int kb = (ks * 64 + lhi * 16) ^ ((r & 7) << 4);
                bfr[n] = *(const bf16x8*)((const char*)Bs + r * 128 + kb);
            }
#pragma unroll
            for (int m = 0; m < 2; m++)
#pragma unroll
                for (int n = 0; n < 4; n++)
                    acc[m][n] = __builtin_amdgcn_mfma_f32_16x16x32_bf16(
                        af[m], bfr[n], acc[m][n], 0, 0, 0);
        }
        __syncthreads();
    }
#pragma unroll
    for (int n = 0; n < 4; n++) {
        int col = col0 + wc * 64 + n * 16 + l15;
        float bv = bias[col];
#pragma unroll
        for (int m = 0; m < 2; m++) {
            int row = row0 + wr * 32 + m * 16 + lhi * 4;
#pragma unroll
            for (int i = 0; i < 4; i++)
                C[(size_t)(row + i) * N + col] = acc[m][n][i] + bv;
        }
    }
}

// ---------------- causal GQA flash attention ----------------
// Swapped QK^T (S^T fragments) + in-register PV via 16x16x16 MFMA.
// V LDS: 8B-granule XOR-(d&15) swizzle -> conflict-free b64 reads
// (low bit baked in global layout, high bits via staging source permute).
__global__ __launch_bounds__(256) void k_attn(
    const u16* __restrict__ Q, const u16* __restrict__ K,
    const u16* __restrict__ Vt, u16* __restrict__ Aout) {
    int i0 = blockIdx.x;
    int u = i0 >> 5;
    int qt = (u < 16) ? (31 - u) : (u - 16);   // CU-sibling work sums constant
    int bh = i0 & 31;
    int b = bh >> 4, h = bh & 15, g = h >> 2;
    int tid = threadIdx.x;
    int lane = tid & 63, wid = tid >> 6;
    int l15 = lane & 15, lhi = lane >> 4;

    const u16* Kp = K + ((size_t)(b * NG + g)) * T_SEQ * DH;
    const u16* Vp = Vt + ((size_t)(b * NG + g)) * DH * T_SEQ;

    __shared__ __align__(16) u16 Ks[2][64 * 64];   // [s][d] 16B-swz, 8KB each
    __shared__ __align__(16) u16 Vs[2][64 * 64];   // [d][s] 8B-swz, 8KB each

    const u16* Qp = Q + ((size_t)bh * T_SEQ + qt * 64) * DH;
    bf16x8 qf[2];   // B-operand: col=q=wid*16+l15, k=d=ks*32+lhi*8+j
#pragma unroll
    for (int ks = 0; ks < 2; ks++)
        qf[ks] = *(const bf16x8*)(Qp + (size_t)(wid * 16 + l15) * DH + ks * 32 + lhi * 8);

    f32x4 of[4] = {};
    float m_i = -3.0e38f, l_i = 0.f;

    int nt = qt + 1;
    int swz = (l15 & 7) << 4;   // K-read 16B swizzle term

    // staging addresses (chunk = 16B); advance by constant per iter
    int c0 = tid, c1 = tid + 256;
    int rk0 = c0 >> 3, rk1 = c1 >> 3;
    int sk0 = (c0 & 7) ^ (rk0 & 7);
    int sk1 = (c1 & 7) ^ (rk1 & 7);
    int sv0 = (c0 & 7) ^ ((rk0 >> 1) & 7);
    int sv1 = (c1 & 7) ^ ((rk1 >> 1) & 7);
    const u16* kg0 = Kp + rk0 * DH + sk0 * 8;
    const u16* kg1 = Kp + rk1 * DH + sk1 * 8;
    const u16* vg0 = Vp + (size_t)rk0 * T_SEQ + sv0 * 8;
    const u16* vg1 = Vp + (size_t)rk1 * T_SEQ + sv1 * 8;

    // prologue: stage tile 0 into buf 0
    async16(kg0, &Ks[0][c0 * 8]);
    async16(kg1, &Ks[0][c1 * 8]);
    async16(vg0, &Vs[0][c0 * 8]);
    async16(vg1, &Vs[0][c1 * 8]);
    __syncthreads();

#pragma unroll 1
    for (int it = 0; it < nt; it++) {
        int cur = it & 1;
        if (it + 1 < nt) {   // next-tile loads fly under this iter's compute
            int nx = cur ^ 1;
            int ko = (it + 1) << 12;   // *64*64 elems
            int vo = (it + 1) << 6;    // *64 elems
            async16(kg0 + ko, &Ks[nx][c0 * 8]);
            async16(kg1 + ko, &Ks[nx][c1 * 8]);
            async16(vg0 + vo, &Vs[nx][c0 * 8]);
            async16(vg1 + vo, &Vs[nx][c1 * 8]);
        }
        const u16* Kc = Ks[cur];
        const u16* Vc = Vs[cur];

        // S^T = K Q^T (exp2 units): sf[n][i] = S[s=n*16+lhi*4+i][q=wid*16+l15]
        f32x4 sf[4] = {};
        __builtin_amdgcn_s_setprio(1);
#pragma unroll
        for (int ks = 0; ks < 2; ks++)
#pragma unroll
            for (int n = 0; n < 4; n++) {
                int kb = (ks * 64 + lhi * 16) ^ swz;
                bf16x8 kf = *(const bf16x8*)((const char*)Kc + (n * 16 + l15) * 128 + kb);
                sf[n] = __builtin_amdgcn_mfma_f32_16x16x32_bf16(kf, qf[ks], sf[n], 0, 0, 0);
            }
        __builtin_amdgcn_s_setprio(0);

        if (it == nt - 1) {   // diagonal tile: causal mask (s > q)
            int qrow = qt * 64 + wid * 16 + l15;
            int sb = it * 64 + lhi * 4;
#pragma unroll
            for (int n = 0; n < 4; n++)
#pragma unroll
                for (int i = 0; i < 4; i++)
                    if (sb + n * 16 + i > qrow) sf[n][i] = -3.0e38f;
        }

        // per-thread partial max over this thread's 16 s-values (one q-row)
        float pmt = sf[0][0];
#pragma unroll
        for (int n = 0; n < 4; n++)
#pragma unroll
            for (int i = 0; i < 4; i++)
                pmt = fmaxf(pmt, sf[n][i]);
        if (!__all(pmt - m_i <= 8.f)) {   // rare: rescale path
#pragma unroll
            for (int off = 16; off <= 32; off <<= 1)
                pmt = fmaxf(pmt, __shfl_xor(pmt, off));   // row-max (4 lanes)
            float mn = fmaxf(m_i, pmt);
            float sc = fexp2(m_i - mn);
            m_i = mn;
            l_i *= sc;
            float sc4[4];
#pragma unroll
            for (int i = 0; i < 4; i++)
                sc4[i] = __shfl(sc, lhi * 4 + i);   // sc for output rows
#pragma unroll
            for (int n = 0; n < 4; n++)
#pragma unroll
                for (int i = 0; i < 4; i++)
                    of[n][i] *= sc4[i];
        }
        // exp + per-thread partial row-sum; pack P to bf16 A-fragments
        bf16x4 pa[4];
#pragma unroll
        for (int n = 0; n < 4; n++) {
#pragma unroll
            for (int i = 0; i < 4; i++) {
                float p = fexp2(sf[n][i] - m_i);
                sf[n][i] = p;
                l_i += p;
            }
            union { uint32_t u[2]; bf16x4 v; } pu;
            pu.u[0] = cvtpk_bf16(sf[n][0], sf[n][1]);
            pu.u[1] = cvtpk_bf16(sf[n][2], sf[n][3]);
            pa[n] = pu.v;
        }

        // O += P V : 16x16x16 MFMAs, A=pa (in-register), B=V^T b64 from LDS
        __builtin_amdgcn_s_setprio(1);
#pragma unroll
        for (int nd = 0; nd < 4; nd++) {
            int rowb = (nd * 16 + l15) * 128;
#pragma unroll
            for (int n = 0; n < 4; n++) {
                int kb = ((4 * n + lhi) ^ l15) << 3;   // 8B-granule swizzle
                bf16x4 vf = *(const bf16x4*)((const char*)Vc + rowb + kb);
                of[nd] = mfma16(pa[n], vf, of[nd]);
            }
        }
        __builtin_amdgcn_s_setprio(0);
        __syncthreads();   // next-tile loads drained here (flew under compute)
    }

    // epilogue: row-sum across the 4 lhi lanes, fetch sums for output rows
#pragma unroll
    for (int off = 16; off <= 32; off <<= 1)
        l_i += __shfl_xor(l_i, off);
    float lq[4];
#pragma unroll
    for (int i = 0; i < 4; i++)
        lq[i] = __shfl(l_i, lhi * 4 + i);
#pragma unroll
    for (int n = 0; n < 4; n++)
#pragma unroll
        for (int i = 0; i < 4; i++) {
            int trow = qt * 64 + wid * 16 + lhi * 4 + i;
            float v = of[n][i] / lq[i];
            Aout[((size_t)(b * T_SEQ + trow)) * DM + h * 64 + n * 16 + l15] = f2bf(v);
        }
}

// ---------------- launch ----------------
extern "C" void kernel_launch(void* const* d_in, const int* in_sizes, int n_in,
                              void* d_out, int out_size, void* d_ws, size_t ws_size,
                              hipStream_t stream) {
    const float* x  = (const float*)d_in[0];
    const float* Wq = (const float*)d_in[1];
    const float* bq = (const float*)d_in[2];
    const float* Wk = (const float*)d_in[3];
    const float* bk = (const float*)d_in[4];
    const float* Wv = (const float*)d_in[5];
    const float* bv = (const float*)d_in[6];
    const float* Wo = (const float*)d_in[7];
    const float* bo = (const float*)d_in[8];

    char* ws = (char*)d_ws;
    size_t o = 0;
    u16*   xb    = (u16*)(ws + o);  o += (size_t)4096 * 1024 * 2;
    u16*   wqkvt = (u16*)(ws + o);  o += (size_t)1536 * 1024 * 2;
    u16*   wot   = (u16*)(ws + o);  o += (size_t)1024 * 1024 * 2;
    float* bqkv  = (float*)(ws + o); o += 1536 * 4;
    o = (o + 255) & ~(size_t)255;
    u16*   Qb    = (u16*)(ws + o);  o += (size_t)2 * NH * T_SEQ * DH * 2;
    u16*   Kb    = (u16*)(ws + o);  o += (size_t)2 * NG * T_SEQ * DH * 2;
    u16*   Vtb   = (u16*)(ws + o);  o += (size_t)2 * NG * DH * T_SEQ * 2;
    u16*   attnb = (u16*)(ws + o);  o += (size_t)4096 * 1024 * 2;
    float2* tbl  = (float2*)(ws + o); o += (size_t)2048 * 32 * 8;

    k_prep<<<4870, 256, 0, stream>>>(x, xb, Wq, Wk, Wv, Wo, wqkvt, wot, bq, bk, bv, bqkv, tbl);
    k_gemm_qkv<<<dim3(12, 64), 256, 0, stream>>>(xb, wqkvt, bqkv, tbl, Qb, Kb, Vtb);
    k_attn<<<1024, 256, 0, stream>>>(Qb, Kb, Vtb, attnb);
    k_gemm_out<<<dim3(8, 64), 256, 0, stream>>>(attnb, wot, bo, (float*)d_out, 4096, 1024, 1024);
}